// Round 4
// baseline (387.057 us; speedup 1.0000x reference)
//
#include <hip/hip_runtime.h>
#include <stdint.h>

#define HID   1024
#define NHEAD 16
#define HDIM  64
#define NV    2048
#define NA    16
#define NTOK  2064
#define BSZ   2
#define MROWS 4128   // 4096 video rows + 32 action rows
#define WSZ   1048576
// p = exp2(s * SCALE * log2(e) - 16)   [fixed-max softmax, exact after divide]
#define EXP_C1 0.18033688011112042f
#define EXP_C2 16.0f

typedef __bf16 bf16x8 __attribute__((ext_vector_type(8)));
typedef unsigned short u16x8 __attribute__((ext_vector_type(8)));
typedef unsigned short u16x4 __attribute__((ext_vector_type(4)));
typedef float f32x4 __attribute__((ext_vector_type(4)));

__device__ __forceinline__ unsigned short f2bf(float f) {  // RNE
  unsigned u = __builtin_bit_cast(unsigned, f);
  u += 0x7FFFu + ((u >> 16) & 1u);
  return (unsigned short)(u >> 16);
}
__device__ __forceinline__ unsigned short f2bf_trunc(float f) {
  return (unsigned short)(__builtin_bit_cast(unsigned, f) >> 16);
}
__device__ __forceinline__ void async_copy16(const void* g, void* l) {
  __builtin_amdgcn_global_load_lds(
      (const __attribute__((address_space(1))) unsigned int*)g,
      (__attribute__((address_space(3))) unsigned int*)l, 16, 0, 0);
}

// ---------------------------------------------------------------------------
// Kernel 0: fp32 -> bf16 convert. Wb = [Wq,Wk,Wv,Wqa,Wka,Wva,Wp,Wpa] (8 x 1M),
// Xb = video (rows 0..4095) || action (rows 4096..4127), row-major 1024.
// ---------------------------------------------------------------------------
__global__ __launch_bounds__(256) void cvt_kernel(
    const float* __restrict__ W0, const float* __restrict__ W1,
    const float* __restrict__ W2, const float* __restrict__ W3,
    const float* __restrict__ W4, const float* __restrict__ W5,
    const float* __restrict__ W6, const float* __restrict__ W7,
    const float* __restrict__ video, const float* __restrict__ action,
    unsigned short* __restrict__ Wb, unsigned short* __restrict__ Xb)
{
  const int y = blockIdx.y;
  const size_t idx = ((size_t)blockIdx.x * 256 + threadIdx.x) * 8;
  const float* src; unsigned short* dst;
  if      (y == 0)  { src = W0; dst = Wb; }
  else if (y == 1)  { src = W1; dst = Wb + 1 * WSZ; }
  else if (y == 2)  { src = W2; dst = Wb + 2 * WSZ; }
  else if (y == 3)  { src = W3; dst = Wb + 3 * WSZ; }
  else if (y == 4)  { src = W4; dst = Wb + 4 * WSZ; }
  else if (y == 5)  { src = W5; dst = Wb + 5 * WSZ; }
  else if (y == 6)  { src = W6; dst = Wb + 6 * WSZ; }
  else if (y == 7)  { src = W7; dst = Wb + 7 * WSZ; }
  else if (y < 12)  { src = video + (size_t)(y - 8) * WSZ; dst = Xb + (size_t)(y - 8) * WSZ; }
  else              { if (idx >= (size_t)BSZ * NA * HID) return;
                      src = action; dst = Xb + (size_t)4096 * HID; }
  float4 f0 = *(const float4*)(src + idx);
  float4 f1 = *(const float4*)(src + idx + 4);
  u16x8 v;
  v[0]=f2bf(f0.x); v[1]=f2bf(f0.y); v[2]=f2bf(f0.z); v[3]=f2bf(f0.w);
  v[4]=f2bf(f1.x); v[5]=f2bf(f1.y); v[6]=f2bf(f1.z); v[7]=f2bf(f1.w);
  *(u16x8*)(dst + idx) = v;
}

// row -> (batch, token) in the joint (B,H,NTOK,D) space
__device__ __forceinline__ void row2bt(int rg, int& b, int& tok, bool& valid) {
  if (rg < 4096) { b = rg >> 11; tok = rg & 2047; valid = true; }
  else { int t = rg - 4096; b = t >> 4; tok = 2048 + (t & 15); valid = rg < MROWS; }
}

// ---------------------------------------------------------------------------
// Kernel 1: QKV GEMM, 128x128 tile, BK=32, ONE-BARRIER double-buffered
// global_load_lds pipeline. grid (8 n-tiles, 33 m-tiles, 3 z); block 256.
// ---------------------------------------------------------------------------
__global__ __launch_bounds__(256) void qkv128_kernel(
    const unsigned short* __restrict__ Xb, const unsigned short* __restrict__ Wb,
    const float* __restrict__ bq, const float* __restrict__ bk,
    const float* __restrict__ bv, const float* __restrict__ bqa,
    const float* __restrict__ bka, const float* __restrict__ bva,
    unsigned short* __restrict__ Qo, unsigned short* __restrict__ Ko,
    unsigned short* __restrict__ Vt)
{
  __shared__ unsigned short As[2][128 * 32];
  __shared__ unsigned short Bs[2][128 * 32];

  const int tid  = threadIdx.x;
  const int w    = tid >> 6;
  const int l    = tid & 63;
  const int quad = l >> 4;
  const int l16  = l & 15;
  const int lrow = l >> 2;
  const int lk   = (l & 3) * 8;
  const int z    = blockIdx.z;
  const int m0   = blockIdx.y * 128;
  const int n0   = blockIdx.x * 128;
  const bool atile = (blockIdx.y == 32);

  const unsigned short* Wm = Wb + (size_t)(atile ? 3 + z : z) * WSZ;
  const float* bias = (z == 0) ? (atile ? bqa : bq)
                    : (z == 1) ? (atile ? bka : bk)
                               : (atile ? bva : bv);

  // staging source pointers (k-offset added in loop)
  const int trow0 = w * 32, trow1 = w * 32 + 16;
  const unsigned short* pa0 = Xb + (size_t)min(m0 + trow0 + lrow, MROWS - 1) * HID + lk;
  const unsigned short* pa1 = Xb + (size_t)min(m0 + trow1 + lrow, MROWS - 1) * HID + lk;
  const unsigned short* pb0 = Wm + (size_t)(n0 + trow0 + lrow) * HID + lk;
  const unsigned short* pb1 = Wm + (size_t)(n0 + trow1 + lrow) * HID + lk;

  const int am = (w & 1) * 64;
  const int bn = (w >> 1) * 64;

  f32x4 acc[4][4] = {};

  // prologue: prefetch kt=0 into buffer 0
  async_copy16(pa0, &As[0][trow0 * 32]);
  async_copy16(pa1, &As[0][trow1 * 32]);
  async_copy16(pb0, &Bs[0][trow0 * 32]);
  async_copy16(pb1, &Bs[0][trow1 * 32]);

  for (int kt = 0; kt < 32; kt++) {
    const int cur = kt & 1;
    __syncthreads();  // drains DMA into buf[cur]; frees buf[cur^1]
    if (kt < 31) {
      const int kn = (kt + 1) * 32;
      async_copy16(pa0 + kn, &As[cur ^ 1][trow0 * 32]);
      async_copy16(pa1 + kn, &As[cur ^ 1][trow1 * 32]);
      async_copy16(pb0 + kn, &Bs[cur ^ 1][trow0 * 32]);
      async_copy16(pb1 + kn, &Bs[cur ^ 1][trow1 * 32]);
    }
    bf16x8 af[4], bf[4];
#pragma unroll
    for (int mi = 0; mi < 4; mi++)
      af[mi] = __builtin_bit_cast(bf16x8, *(const u16x8*)&As[cur][(am + mi * 16 + l16) * 32 + quad * 8]);
#pragma unroll
    for (int ni = 0; ni < 4; ni++)
      bf[ni] = __builtin_bit_cast(bf16x8, *(const u16x8*)&Bs[cur][(bn + ni * 16 + l16) * 32 + quad * 8]);
#pragma unroll
    for (int mi = 0; mi < 4; mi++)
#pragma unroll
      for (int ni = 0; ni < 4; ni++)
        acc[mi][ni] = __builtin_amdgcn_mfma_f32_16x16x32_bf16(af[mi], bf[ni], acc[mi][ni], 0, 0, 0);
  }

  if (z < 2) {
    unsigned short* O = (z == 0) ? Qo : Ko;
#pragma unroll
    for (int mi = 0; mi < 4; mi++) {
      const int rgb = m0 + am + mi * 16 + quad * 4;
#pragma unroll
      for (int ni = 0; ni < 4; ni++) {
        const int gcol = n0 + bn + ni * 16 + l16;
        const int head = gcol >> 6, col = gcol & 63;
        const float bias_v = bias[gcol];
        const int seg = (col >= 40) ? 2 : (col >= 20) ? 1 : 0;
        const int tin = col - seg * 20;
        const float om = exp2f(-(float)(tin >> 1) * 1.3287712379549449f);
        const bool evn = !(tin & 1);
#pragma unroll
        for (int r = 0; r < 4; r++) {
          int rg = rgb + r;
          int b, tok; bool valid;
          row2bt(rg, b, tok, valid);
          float val = acc[mi][ni][r] + bias_v;
          float part = __shfl_xor(val, 1);
          if (tok < 2048 && col < 60) {
            int dp = tok >> 8, hp = (tok >> 4) & 15, wp = tok & 15;
            float pos = (seg == 0) ? (float)dp : (seg == 1) ? (float)hp : (float)wp;
            float fr = pos * om;
            float cs = cosf(fr), sn = sinf(fr);
            val = evn ? (val * cs - part * sn) : (val * cs + part * sn);
          }
          if (valid)
            O[(((size_t)b * NHEAD + head) * NTOK + tok) * HDIM + col] = f2bf(val);
        }
      }
    }
  } else {
#pragma unroll
    for (int mi = 0; mi < 4; mi++) {
      const int rgb = m0 + am + mi * 16 + quad * 4;
      int b, tok; bool valid;
      row2bt(rgb, b, tok, valid);
#pragma unroll
      for (int ni = 0; ni < 4; ni++) {
        const int gcol = n0 + bn + ni * 16 + l16;
        const int head = gcol >> 6, d = gcol & 63;
        const float bias_v = bias[gcol];
        u16x4 pk;
#pragma unroll
        for (int r = 0; r < 4; r++) pk[r] = f2bf(acc[mi][ni][r] + bias_v);
        if (valid)
          *(u16x4*)&Vt[(((size_t)b * NHEAD + head) * HDIM + d) * NTOK + tok] = pk;
      }
    }
  }
}

// ---------------------------------------------------------------------------
// Kernel 2: flash attention, fixed-max softmax, register-prefetch pipelined
// K/V staging (one barrier per kv-tile). grid (33 q-tiles, B*H).
// ---------------------------------------------------------------------------
__global__ __launch_bounds__(256) void attn_kernel(
    const unsigned short* __restrict__ Q,
    const unsigned short* __restrict__ K,
    const unsigned short* __restrict__ Vt,
    unsigned short* __restrict__ ctx)
{
  __shared__ unsigned short Qs[64][72];
  __shared__ unsigned short Ks[2][64][72];
  __shared__ unsigned short Vts[2][64][72];
  __shared__ unsigned short Ps[4][16][68];

  const int tid  = threadIdx.x;
  const int wave = tid >> 6;
  const int lane = tid & 63;
  const int quad = lane >> 4;
  const int l16  = lane & 15;
  const int bh   = blockIdx.y;
  const int q0   = blockIdx.x * 64;
  const unsigned short* Qp  = Q  + (size_t)bh * NTOK * HDIM;
  const unsigned short* Kp  = K  + (size_t)bh * NTOK * HDIM;
  const unsigned short* Vtp = Vt + (size_t)bh * HDIM * NTOK;

  const int r  = tid >> 2;
  const int c0 = (tid & 3) * 8;

  {
    int row = min(q0 + r, NTOK - 1);
#pragma unroll
    for (int cc = 0; cc < 2; cc++) {
      int c = c0 + cc * 32;
      *(u16x8*)&Qs[r][c] = *(const u16x8*)(Qp + (size_t)row * HDIM + c);
    }
  }

  u16x8 ones_u;
#pragma unroll
  for (int i = 0; i < 8; i++) ones_u[i] = 0x3F80;
  const bf16x8 ones = __builtin_bit_cast(bf16x8, ones_u);

  f32x4 oacc[4] = {};
  f32x4 lacc = {};

  // prologue: load kv-tile 0 into registers
  u16x8 kreg[2], vreg[2];
  {
    int row = min(r, NTOK - 1);
#pragma unroll
    for (int cc = 0; cc < 2; cc++) {
      int c = c0 + cc * 32;
      kreg[cc] = *(const u16x8*)(Kp + (size_t)row * HDIM + c);
      vreg[cc] = *(const u16x8*)(Vtp + (size_t)r * NTOK + c);
    }
  }

  for (int it = 0; it < 33; it++) {
    const int cur = it & 1;
    const int kv0 = it * 64;
    // stage current tile from regs (buf[cur] free: its readers at it-2 done by barrier it-1)
#pragma unroll
    for (int cc = 0; cc < 2; cc++) {
      int c = c0 + cc * 32;
      *(u16x8*)&Ks[cur][r][c]  = kreg[cc];
      *(u16x8*)&Vts[cur][r][c] = vreg[cc];
    }
    __syncthreads();
    // prefetch next tile into regs (latency hidden behind compute below)
    if (it < 32) {
      int row = min(kv0 + 64 + r, NTOK - 1);
#pragma unroll
      for (int cc = 0; cc < 2; cc++) {
        int c = c0 + cc * 32;
        kreg[cc] = *(const u16x8*)(Kp + (size_t)row * HDIM + c);
        vreg[cc] = *(const u16x8*)(Vtp + (size_t)r * NTOK + kv0 + 64 + c);
      }
    }

    // S = Q K^T
    f32x4 sacc[4] = {};
#pragma unroll
    for (int kq = 0; kq < 64; kq += 32) {
      bf16x8 a = __builtin_bit_cast(bf16x8, *(const u16x8*)&Qs[wave * 16 + l16][kq + quad * 8]);
#pragma unroll
      for (int nt = 0; nt < 4; nt++) {
        bf16x8 bb = __builtin_bit_cast(bf16x8, *(const u16x8*)&Ks[cur][nt * 16 + l16][kq + quad * 8]);
        sacc[nt] = __builtin_amdgcn_mfma_f32_16x16x32_bf16(a, bb, sacc[nt], 0, 0, 0);
      }
    }

    // p = exp2(s*C1 - C2); tail keys masked. Wave-private Ps round-trip.
#pragma unroll
    for (int nt = 0; nt < 4; nt++) {
      bool valid = (kv0 + nt * 16 + l16) < NTOK;
#pragma unroll
      for (int rr = 0; rr < 4; rr++) {
        float p = exp2f(__builtin_fmaf(sacc[nt][rr], EXP_C1, -EXP_C2));
        p = valid ? p : 0.f;
        Ps[wave][quad * 4 + rr][nt * 16 + l16] = f2bf_trunc(p);
      }
    }

    // O += P V ; l += P @ ones
#pragma unroll
    for (int kq = 0; kq < 64; kq += 32) {
      u16x4 alo = *(const u16x4*)&Ps[wave][l16][kq + quad * 8];
      u16x4 ahi = *(const u16x4*)&Ps[wave][l16][kq + quad * 8 + 4];
      bf16x8 a = __builtin_bit_cast(bf16x8,
          __builtin_shufflevector(alo, ahi, 0, 1, 2, 3, 4, 5, 6, 7));
#pragma unroll
      for (int nt = 0; nt < 4; nt++) {
        bf16x8 bb = __builtin_bit_cast(bf16x8, *(const u16x8*)&Vts[cur][nt * 16 + l16][kq + quad * 8]);
        oacc[nt] = __builtin_amdgcn_mfma_f32_16x16x32_bf16(a, bb, oacc[nt], 0, 0, 0);
      }
      lacc = __builtin_amdgcn_mfma_f32_16x16x32_bf16(a, ones, lacc, 0, 0, 0);
    }
  }

  const int b = bh >> 4, h = bh & 15;
  float rl[4];
#pragma unroll
  for (int rr = 0; rr < 4; rr++) rl[rr] = 1.f / lacc[rr];
#pragma unroll
  for (int nt = 0; nt < 4; nt++) {
#pragma unroll
    for (int rr = 0; rr < 4; rr++) {
      int token = q0 + wave * 16 + quad * 4 + rr;
      if (token < NTOK) {
        int row = (token < 2048) ? (b * 2048 + token) : (4096 + b * NA + (token - 2048));
        int d = nt * 16 + l16;
        ctx[(size_t)row * HID + h * HDIM + d] = f2bf(oacc[nt][rr] * rl[rr]);
      }
    }
  }
}

// ---------------------------------------------------------------------------
// Kernel 3: output projection, 128x128 tile, pipelined like qkv128.
// ---------------------------------------------------------------------------
__global__ __launch_bounds__(256) void proj128_kernel(
    const unsigned short* __restrict__ ctx, const unsigned short* __restrict__ Wb,
    const float* __restrict__ bp, const float* __restrict__ bpa,
    float* __restrict__ out)
{
  __shared__ unsigned short As[2][128 * 32];
  __shared__ unsigned short Bs[2][128 * 32];

  const int tid  = threadIdx.x;
  const int w    = tid >> 6;
  const int l    = tid & 63;
  const int quad = l >> 4;
  const int l16  = l & 15;
  const int lrow = l >> 2;
  const int lk   = (l & 3) * 8;
  const int m0   = blockIdx.y * 128;
  const int n0   = blockIdx.x * 128;
  const bool atile = (blockIdx.y == 32);

  const unsigned short* Wm = Wb + (size_t)(atile ? 7 : 6) * WSZ;
  const float* bias = atile ? bpa : bp;

  const int trow0 = w * 32, trow1 = w * 32 + 16;
  const unsigned short* pa0 = ctx + (size_t)min(m0 + trow0 + lrow, MROWS - 1) * HID + lk;
  const unsigned short* pa1 = ctx + (size_t)min(m0 + trow1 + lrow, MROWS - 1) * HID + lk;
  const unsigned short* pb0 = Wm + (size_t)(n0 + trow0 + lrow) * HID + lk;
  const unsigned short* pb1 = Wm + (size_t)(n0 + trow1 + lrow) * HID + lk;

  const int am = (w & 1) * 64;
  const int bn = (w >> 1) * 64;

  f32x4 acc[4][4] = {};

  async_copy16(pa0, &As[0][trow0 * 32]);
  async_copy16(pa1, &As[0][trow1 * 32]);
  async_copy16(pb0, &Bs[0][trow0 * 32]);
  async_copy16(pb1, &Bs[0][trow1 * 32]);

  for (int kt = 0; kt < 32; kt++) {
    const int cur = kt & 1;
    __syncthreads();
    if (kt < 31) {
      const int kn = (kt + 1) * 32;
      async_copy16(pa0 + kn, &As[cur ^ 1][trow0 * 32]);
      async_copy16(pa1 + kn, &As[cur ^ 1][trow1 * 32]);
      async_copy16(pb0 + kn, &Bs[cur ^ 1][trow0 * 32]);
      async_copy16(pb1 + kn, &Bs[cur ^ 1][trow1 * 32]);
    }
    bf16x8 af[4], bf[4];
#pragma unroll
    for (int mi = 0; mi < 4; mi++)
      af[mi] = __builtin_bit_cast(bf16x8, *(const u16x8*)&As[cur][(am + mi * 16 + l16) * 32 + quad * 8]);
#pragma unroll
    for (int ni = 0; ni < 4; ni++)
      bf[ni] = __builtin_bit_cast(bf16x8, *(const u16x8*)&Bs[cur][(bn + ni * 16 + l16) * 32 + quad * 8]);
#pragma unroll
    for (int mi = 0; mi < 4; mi++)
#pragma unroll
      for (int ni = 0; ni < 4; ni++)
        acc[mi][ni] = __builtin_amdgcn_mfma_f32_16x16x32_bf16(af[mi], bf[ni], acc[mi][ni], 0, 0, 0);
  }

#pragma unroll
  for (int mi = 0; mi < 4; mi++) {
    const int rgb = m0 + am + mi * 16 + quad * 4;
#pragma unroll
    for (int ni = 0; ni < 4; ni++) {
      const int gcol = n0 + bn + ni * 16 + l16;
      const float bias_v = bias[gcol];
#pragma unroll
      for (int r = 0; r < 4; r++) {
        int rg = rgb + r;
        if (rg < MROWS) out[(size_t)rg * HID + gcol] = acc[mi][ni][r] + bias_v;
      }
    }
  }
}

// ---------------------------------------------------------------------------
extern "C" void kernel_launch(void* const* d_in, const int* in_sizes, int n_in,
                              void* d_out, int out_size, void* d_ws, size_t ws_size,
                              hipStream_t stream) {
  const float* A[18];
  if (in_sizes[0] == HID * HID) {
    for (int i = 0; i < 18; i++) A[i] = (const float*)d_in[i];
  } else {
    A[16] = (const float*)d_in[0];
    A[17] = (const float*)d_in[1];
    for (int i = 0; i < 16; i++) A[i] = (const float*)d_in[i + 2];
  }
  const float *Wq = A[0], *bq = A[1], *Wk = A[2], *bk = A[3], *Wv = A[4], *bv = A[5];
  const float *Wqa = A[6], *bqa = A[7], *Wka = A[8], *bka = A[9], *Wva = A[10], *bva = A[11];
  const float *Wp = A[12], *bp = A[13], *Wpa = A[14], *bpa = A[15];
  const float *video = A[16], *action = A[17];
  float* out = (float*)d_out;

  const size_t qkv_elems = (size_t)BSZ * NHEAD * NTOK * HDIM;  // 4,227,072
  unsigned short* Wb  = (unsigned short*)d_ws;                  // 8 x 1M bf16
  unsigned short* Xb  = Wb + (size_t)8 * WSZ;                   // 4128 x 1024
  unsigned short* Qw  = Xb + (size_t)MROWS * HID;
  unsigned short* Kw  = Qw + qkv_elems;
  unsigned short* Vtw = Kw + qkv_elems;                         // (B,H,D,NTOK)
  unsigned short* ctx = Vtw + qkv_elems;                        // 4128 x 1024 bf16

  dim3 g0(512, 13);
  cvt_kernel<<<g0, 256, 0, stream>>>(Wq, Wk, Wv, Wqa, Wka, Wva, Wp, Wpa,
                                     video, action, Wb, Xb);
  dim3 g1(8, 33, 3);
  qkv128_kernel<<<g1, 256, 0, stream>>>(Xb, Wb, bq, bk, bv, bqa, bka, bva,
                                        Qw, Kw, Vtw);
  dim3 g2(33, BSZ * NHEAD);
  attn_kernel<<<g2, 256, 0, stream>>>(Qw, Kw, Vtw, ctx);
  dim3 g3(8, 33);
  proj128_kernel<<<g3, 256, 0, stream>>>(ctx, Wb, bp, bpa, out);
}

// Round 5
// 380.577 us; speedup vs baseline: 1.0170x; 1.0170x over previous
//
#include <hip/hip_runtime.h>
#include <stdint.h>

#define HID   1024
#define NHEAD 16
#define HDIM  64
#define NV    2048
#define NA    16
#define NTOK  2064
#define BSZ   2
#define MROWS 4128   // 4096 video rows + 32 action rows
#define WSZ   1048576
// p = exp2(s * SCALE * log2(e) - 16)   [fixed-max softmax, exact after divide]
#define EXP_C1 0.18033688011112042f
#define EXP_C2 16.0f

typedef __bf16 bf16x8 __attribute__((ext_vector_type(8)));
typedef unsigned short u16x8 __attribute__((ext_vector_type(8)));
typedef unsigned short u16x4 __attribute__((ext_vector_type(4)));
typedef float f32x4 __attribute__((ext_vector_type(4)));

__device__ __forceinline__ unsigned short f2bf(float f) {  // RNE
  unsigned u = __builtin_bit_cast(unsigned, f);
  u += 0x7FFFu + ((u >> 16) & 1u);
  return (unsigned short)(u >> 16);
}
__device__ __forceinline__ unsigned short f2bf_trunc(float f) {
  return (unsigned short)(__builtin_bit_cast(unsigned, f) >> 16);
}
__device__ __forceinline__ void async_copy16(const void* g, void* l) {
  __builtin_amdgcn_global_load_lds(
      (const __attribute__((address_space(1))) unsigned int*)g,
      (__attribute__((address_space(3))) unsigned int*)l, 16, 0, 0);
}

// ---------------------------------------------------------------------------
// Kernel 0: fp32 -> bf16 convert. Wb = [Wq,Wk,Wv,Wqa,Wka,Wva,Wp,Wpa] (8 x 1M),
// Xb = video (rows 0..4095) || action (rows 4096..4127), row-major 1024.
// ---------------------------------------------------------------------------
__global__ __launch_bounds__(256) void cvt_kernel(
    const float* __restrict__ W0, const float* __restrict__ W1,
    const float* __restrict__ W2, const float* __restrict__ W3,
    const float* __restrict__ W4, const float* __restrict__ W5,
    const float* __restrict__ W6, const float* __restrict__ W7,
    const float* __restrict__ video, const float* __restrict__ action,
    unsigned short* __restrict__ Wb, unsigned short* __restrict__ Xb)
{
  const int y = blockIdx.y;
  const size_t idx = ((size_t)blockIdx.x * 256 + threadIdx.x) * 8;
  const float* src; unsigned short* dst;
  if      (y == 0)  { src = W0; dst = Wb; }
  else if (y == 1)  { src = W1; dst = Wb + 1 * WSZ; }
  else if (y == 2)  { src = W2; dst = Wb + 2 * WSZ; }
  else if (y == 3)  { src = W3; dst = Wb + 3 * WSZ; }
  else if (y == 4)  { src = W4; dst = Wb + 4 * WSZ; }
  else if (y == 5)  { src = W5; dst = Wb + 5 * WSZ; }
  else if (y == 6)  { src = W6; dst = Wb + 6 * WSZ; }
  else if (y == 7)  { src = W7; dst = Wb + 7 * WSZ; }
  else if (y < 12)  { src = video + (size_t)(y - 8) * WSZ; dst = Xb + (size_t)(y - 8) * WSZ; }
  else              { if (idx >= (size_t)BSZ * NA * HID) return;
                      src = action; dst = Xb + (size_t)4096 * HID; }
  float4 f0 = *(const float4*)(src + idx);
  float4 f1 = *(const float4*)(src + idx + 4);
  u16x8 v;
  v[0]=f2bf(f0.x); v[1]=f2bf(f0.y); v[2]=f2bf(f0.z); v[3]=f2bf(f0.w);
  v[4]=f2bf(f1.x); v[5]=f2bf(f1.y); v[6]=f2bf(f1.z); v[7]=f2bf(f1.w);
  *(u16x8*)(dst + idx) = v;
}

// row -> (batch, token) in the joint (B,H,NTOK,D) space
__device__ __forceinline__ void row2bt(int rg, int& b, int& tok, bool& valid) {
  if (rg < 4096) { b = rg >> 11; tok = rg & 2047; valid = true; }
  else { int t = rg - 4096; b = t >> 4; tok = 2048 + (t & 15); valid = rg < MROWS; }
}

// ---------------------------------------------------------------------------
// Kernel 1: fused QKV GEMM. One block computes Q,K,V for the same 128m x 64n
// tile (n-tile == head), sharing the A staging. grid (16 heads, 33 m-tiles).
// Per iter: A dbuf 128x32, B dbuf 3 x 64x32; 24 MFMA/wave.
// ---------------------------------------------------------------------------
__global__ __launch_bounds__(256, 2) void qkvf_kernel(
    const unsigned short* __restrict__ Xb, const unsigned short* __restrict__ Wb,
    const float* __restrict__ bq, const float* __restrict__ bk,
    const float* __restrict__ bv, const float* __restrict__ bqa,
    const float* __restrict__ bka, const float* __restrict__ bva,
    unsigned short* __restrict__ Qo, unsigned short* __restrict__ Ko,
    unsigned short* __restrict__ Vt)
{
  __shared__ unsigned short As[2][128 * 32];      // 16 KB
  __shared__ unsigned short Bs[2][3][64 * 32];    // 24 KB

  const int tid  = threadIdx.x;
  const int w    = tid >> 6;
  const int l    = tid & 63;
  const int quad = l >> 4;
  const int l16  = l & 15;
  const int lr4  = l >> 2;          // 0..15
  const int lk   = (l & 3) * 8;     // k-chunk
  const int head = blockIdx.x;
  const int n0   = head * 64;
  const int m0   = blockIdx.y * 128;
  const bool atile = (blockIdx.y == 32);

  const float* biasz[3] = { atile ? bqa : bq, atile ? bka : bk, atile ? bva : bv };

  // staging source pointers
  const unsigned short* pa0 = Xb + (size_t)min(m0 + w * 32 + lr4,      MROWS - 1) * HID + lk;
  const unsigned short* pa1 = Xb + (size_t)min(m0 + w * 32 + 16 + lr4, MROWS - 1) * HID + lk;
  const unsigned short* pbz[3];
#pragma unroll
  for (int z = 0; z < 3; z++)
    pbz[z] = Wb + (size_t)(atile ? 3 + z : z) * WSZ + (size_t)(n0 + w * 16 + lr4) * HID + lk;

  f32x4 acc[3][2][4] = {};

  // prologue: tile 0 into buf 0
  async_copy16(pa0, &As[0][(w * 32) * 32]);
  async_copy16(pa1, &As[0][(w * 32 + 16) * 32]);
#pragma unroll
  for (int z = 0; z < 3; z++) async_copy16(pbz[z], &Bs[0][z][(w * 16) * 32]);

  for (int kt = 0; kt < 32; kt++) {
    const int cur = kt & 1;
    __syncthreads();   // drains DMA into buf[cur]; frees buf[cur^1]
    if (kt < 31) {
      const int kn = (kt + 1) * 32;
      async_copy16(pa0 + kn, &As[cur ^ 1][(w * 32) * 32]);
      async_copy16(pa1 + kn, &As[cur ^ 1][(w * 32 + 16) * 32]);
#pragma unroll
      for (int z = 0; z < 3; z++) async_copy16(pbz[z] + kn, &Bs[cur ^ 1][z][(w * 16) * 32]);
    }
    bf16x8 af[2];
#pragma unroll
    for (int mi = 0; mi < 2; mi++)
      af[mi] = __builtin_bit_cast(bf16x8, *(const u16x8*)&As[cur][(w * 32 + mi * 16 + l16) * 32 + quad * 8]);
#pragma unroll
    for (int z = 0; z < 3; z++) {
#pragma unroll
      for (int ni = 0; ni < 4; ni++) {
        bf16x8 bb = __builtin_bit_cast(bf16x8, *(const u16x8*)&Bs[cur][z][(ni * 16 + l16) * 32 + quad * 8]);
#pragma unroll
        for (int mi = 0; mi < 2; mi++)
          acc[z][mi][ni] = __builtin_amdgcn_mfma_f32_16x16x32_bf16(af[mi], bb, acc[z][mi][ni], 0, 0, 0);
      }
    }
  }

  // epilogues
#pragma unroll
  for (int z = 0; z < 3; z++) {
    const float* bias = biasz[z];
    if (z < 2) {
      unsigned short* O = (z == 0) ? Qo : Ko;
#pragma unroll
      for (int mi = 0; mi < 2; mi++) {
        const int rgb = m0 + w * 32 + mi * 16 + quad * 4;
#pragma unroll
        for (int ni = 0; ni < 4; ni++) {
          const int col = ni * 16 + l16;
          const float bias_v = bias[n0 + col];
          const int seg = (col >= 40) ? 2 : (col >= 20) ? 1 : 0;
          const int tin = col - seg * 20;
          const float om = exp2f(-(float)(tin >> 1) * 1.3287712379549449f);
          const bool evn = !(tin & 1);
#pragma unroll
          for (int r = 0; r < 4; r++) {
            int rg = rgb + r;
            int b, tok; bool valid;
            row2bt(rg, b, tok, valid);
            float val = acc[z][mi][ni][r] + bias_v;
            float part = __shfl_xor(val, 1);
            if (tok < 2048 && col < 60) {
              int dp = tok >> 8, hp = (tok >> 4) & 15, wp = tok & 15;
              float pos = (seg == 0) ? (float)dp : (seg == 1) ? (float)hp : (float)wp;
              float fr = pos * om;
              float cs = cosf(fr), sn = sinf(fr);
              val = evn ? (val * cs - part * sn) : (val * cs + part * sn);
            }
            if (valid)
              O[(((size_t)b * NHEAD + head) * NTOK + tok) * HDIM + col] = f2bf(val);
          }
        }
      }
    } else {
#pragma unroll
      for (int mi = 0; mi < 2; mi++) {
        const int rgb = m0 + w * 32 + mi * 16 + quad * 4;
        int b, tok; bool valid;
        row2bt(rgb, b, tok, valid);
#pragma unroll
        for (int ni = 0; ni < 4; ni++) {
          const int d = ni * 16 + l16;
          const float bias_v = bias[n0 + d];
          u16x4 pk;
#pragma unroll
          for (int r = 0; r < 4; r++) pk[r] = f2bf(acc[z][mi][ni][r] + bias_v);
          if (valid)
            *(u16x4*)&Vt[(((size_t)b * NHEAD + head) * HDIM + d) * NTOK + tok] = pk;
        }
      }
    }
  }
}

// ---------------------------------------------------------------------------
// Kernel 2: flash attention, fixed-max softmax. Single LDS buffer (36 KB ->
// 4 blocks/CU) + register prefetch; mask-free main loop, peeled tail tile.
// grid (33 q-tiles, B*H).
// ---------------------------------------------------------------------------
__global__ __launch_bounds__(256) void attn_kernel(
    const unsigned short* __restrict__ Q,
    const unsigned short* __restrict__ K,
    const unsigned short* __restrict__ Vt,
    unsigned short* __restrict__ ctx)
{
  __shared__ unsigned short Qs[64][72];
  __shared__ unsigned short Ks[64][72];
  __shared__ unsigned short Vts[64][72];
  __shared__ unsigned short Ps[4][16][68];

  const int tid  = threadIdx.x;
  const int wave = tid >> 6;
  const int lane = tid & 63;
  const int quad = lane >> 4;
  const int l16  = lane & 15;
  const int bh   = blockIdx.y;
  const int q0   = blockIdx.x * 64;
  const unsigned short* Qp  = Q  + (size_t)bh * NTOK * HDIM;
  const unsigned short* Kp  = K  + (size_t)bh * NTOK * HDIM;
  const unsigned short* Vtp = Vt + (size_t)bh * HDIM * NTOK;

  const int r  = tid >> 2;
  const int c0 = (tid & 3) * 8;

  {
    int row = min(q0 + r, NTOK - 1);
#pragma unroll
    for (int cc = 0; cc < 2; cc++) {
      int c = c0 + cc * 32;
      *(u16x8*)&Qs[r][c] = *(const u16x8*)(Qp + (size_t)row * HDIM + c);
    }
  }

  u16x8 ones_u;
#pragma unroll
  for (int i = 0; i < 8; i++) ones_u[i] = 0x3F80;
  const bf16x8 ones = __builtin_bit_cast(bf16x8, ones_u);

  f32x4 oacc[4] = {};
  f32x4 lacc = {};

  // prologue: tile 0 (keys 0..63) into regs
  u16x8 kreg[2], vreg[2];
#pragma unroll
  for (int cc = 0; cc < 2; cc++) {
    int c = c0 + cc * 32;
    kreg[cc] = *(const u16x8*)(Kp + (size_t)r * HDIM + c);
    vreg[cc] = *(const u16x8*)(Vtp + (size_t)r * NTOK + c);
  }

  // main loop: 32 full tiles, keys 0..2047, no masking needed
  for (int it = 0; it < 32; it++) {
    const int kv0 = it * 64;
    __syncthreads();   // previous tile's Ks/Vts reads complete
#pragma unroll
    for (int cc = 0; cc < 2; cc++) {
      int c = c0 + cc * 32;
      *(u16x8*)&Ks[r][c]  = kreg[cc];
      *(u16x8*)&Vts[r][c] = vreg[cc];
    }
    __syncthreads();
    if (it < 31) {      // prefetch next tile; latency overlaps compute below
      int row = kv0 + 64 + r;
#pragma unroll
      for (int cc = 0; cc < 2; cc++) {
        int c = c0 + cc * 32;
        kreg[cc] = *(const u16x8*)(Kp + (size_t)row * HDIM + c);
        vreg[cc] = *(const u16x8*)(Vtp + (size_t)r * NTOK + kv0 + 64 + c);
      }
    }

    // S = Q K^T
    f32x4 sacc[4] = {};
#pragma unroll
    for (int kq = 0; kq < 64; kq += 32) {
      bf16x8 a = __builtin_bit_cast(bf16x8, *(const u16x8*)&Qs[wave * 16 + l16][kq + quad * 8]);
#pragma unroll
      for (int nt = 0; nt < 4; nt++) {
        bf16x8 bb = __builtin_bit_cast(bf16x8, *(const u16x8*)&Ks[nt * 16 + l16][kq + quad * 8]);
        sacc[nt] = __builtin_amdgcn_mfma_f32_16x16x32_bf16(a, bb, sacc[nt], 0, 0, 0);
      }
    }

    // p = exp2(s*C1 - C2) -> wave-private Ps (no barrier needed)
#pragma unroll
    for (int nt = 0; nt < 4; nt++)
#pragma unroll
      for (int rr = 0; rr < 4; rr++)
        Ps[wave][quad * 4 + rr][nt * 16 + l16] =
            f2bf_trunc(exp2f(__builtin_fmaf(sacc[nt][rr], EXP_C1, -EXP_C2)));

    // O += P V ; l += P @ ones
#pragma unroll
    for (int kq = 0; kq < 64; kq += 32) {
      u16x4 alo = *(const u16x4*)&Ps[wave][l16][kq + quad * 8];
      u16x4 ahi = *(const u16x4*)&Ps[wave][l16][kq + quad * 8 + 4];
      bf16x8 a = __builtin_bit_cast(bf16x8,
          __builtin_shufflevector(alo, ahi, 0, 1, 2, 3, 4, 5, 6, 7));
#pragma unroll
      for (int nt = 0; nt < 4; nt++) {
        bf16x8 bb = __builtin_bit_cast(bf16x8, *(const u16x8*)&Vts[nt * 16 + l16][kq + quad * 8]);
        oacc[nt] = __builtin_amdgcn_mfma_f32_16x16x32_bf16(a, bb, oacc[nt], 0, 0, 0);
      }
      lacc = __builtin_amdgcn_mfma_f32_16x16x32_bf16(a, ones, lacc, 0, 0, 0);
    }
  }

  // ---- tail tile: keys 2048..2063 (16 valid) ----
  __syncthreads();
  if (tid < 64) {      // K rows 2048..2063 into Ks rows 0..15
    int rr16 = tid >> 2;
#pragma unroll
    for (int cc = 0; cc < 2; cc++) {
      int c = (tid & 3) * 8 + cc * 32;
      *(u16x8*)&Ks[rr16][c] = *(const u16x8*)(Kp + (size_t)(2048 + rr16) * HDIM + c);
    }
  }
  if ((tid & 3) < 2)   // V^T cols 2048..2063 into Vts[d][0..15]
    *(u16x8*)&Vts[r][(tid & 3) * 8] = *(const u16x8*)(Vtp + (size_t)r * NTOK + 2048 + (tid & 3) * 8);
  __syncthreads();
  {
    f32x4 s0 = {};
#pragma unroll
    for (int kq = 0; kq < 64; kq += 32) {
      bf16x8 a = __builtin_bit_cast(bf16x8, *(const u16x8*)&Qs[wave * 16 + l16][kq + quad * 8]);
      bf16x8 bb = __builtin_bit_cast(bf16x8, *(const u16x8*)&Ks[l16][kq + quad * 8]);
      s0 = __builtin_amdgcn_mfma_f32_16x16x32_bf16(a, bb, s0, 0, 0, 0);
    }
#pragma unroll
    for (int rr = 0; rr < 4; rr++) {
      Ps[wave][quad * 4 + rr][l16]      = f2bf_trunc(exp2f(__builtin_fmaf(s0[rr], EXP_C1, -EXP_C2)));
      Ps[wave][quad * 4 + rr][16 + l16] = 0;
    }
    u16x4 alo = *(const u16x4*)&Ps[wave][l16][quad * 8];
    u16x4 ahi = *(const u16x4*)&Ps[wave][l16][quad * 8 + 4];
    bf16x8 a = __builtin_bit_cast(bf16x8,
        __builtin_shufflevector(alo, ahi, 0, 1, 2, 3, 4, 5, 6, 7));
#pragma unroll
    for (int nt = 0; nt < 4; nt++) {
      bf16x8 bb = __builtin_bit_cast(bf16x8, *(const u16x8*)&Vts[nt * 16 + l16][quad * 8]);
      oacc[nt] = __builtin_amdgcn_mfma_f32_16x16x32_bf16(a, bb, oacc[nt], 0, 0, 0);
    }
    lacc = __builtin_amdgcn_mfma_f32_16x16x32_bf16(a, ones, lacc, 0, 0, 0);
  }

  const int b = bh >> 4, h = bh & 15;
  float rl[4];
#pragma unroll
  for (int rr = 0; rr < 4; rr++) rl[rr] = 1.f / lacc[rr];
#pragma unroll
  for (int nt = 0; nt < 4; nt++) {
#pragma unroll
    for (int rr = 0; rr < 4; rr++) {
      int token = q0 + wave * 16 + quad * 4 + rr;
      if (token < NTOK) {
        int row = (token < 2048) ? (b * 2048 + token) : (4096 + b * NA + (token - 2048));
        int d = nt * 16 + l16;
        ctx[(size_t)row * HID + h * HDIM + d] = f2bf(oacc[nt][rr] * rl[rr]);
      }
    }
  }
}

// ---------------------------------------------------------------------------
// Kernel 3: output projection, 128x128 tile, BK=64 double-buffered pipeline.
// grid (8 n-tiles, 33 m-tiles); 264 blocks ~= 1/CU, one round.
// ---------------------------------------------------------------------------
__global__ __launch_bounds__(256, 2) void proj128_kernel(
    const unsigned short* __restrict__ ctx, const unsigned short* __restrict__ Wb,
    const float* __restrict__ bp, const float* __restrict__ bpa,
    float* __restrict__ out)
{
  __shared__ unsigned short As[2][128 * 64];   // 32 KB
  __shared__ unsigned short Bs[2][128 * 64];   // 32 KB

  const int tid  = threadIdx.x;
  const int w    = tid >> 6;
  const int l    = tid & 63;
  const int quad = l >> 4;
  const int l16  = l & 15;
  const int lr8  = l >> 3;          // 0..7
  const int lk   = (l & 7) * 8;     // 0..56
  const int m0   = blockIdx.y * 128;
  const int n0   = blockIdx.x * 128;
  const bool atile = (blockIdx.y == 32);

  const unsigned short* Wm = Wb + (size_t)(atile ? 7 : 6) * WSZ;
  const float* bias = atile ? bpa : bp;

  const unsigned short* pa[4];
  const unsigned short* pb[4];
#pragma unroll
  for (int i = 0; i < 4; i++) {
    pa[i] = ctx + (size_t)min(m0 + w * 32 + i * 8 + lr8, MROWS - 1) * HID + lk;
    pb[i] = Wm + (size_t)(n0 + w * 32 + i * 8 + lr8) * HID + lk;
  }

  const int am = (w & 1) * 64;
  const int bn = (w >> 1) * 64;

  f32x4 acc[4][4] = {};

#pragma unroll
  for (int i = 0; i < 4; i++) {
    async_copy16(pa[i], &As[0][(w * 32 + i * 8) * 64]);
    async_copy16(pb[i], &Bs[0][(w * 32 + i * 8) * 64]);
  }

  for (int kt = 0; kt < 16; kt++) {
    const int cur = kt & 1;
    __syncthreads();
    if (kt < 15) {
      const int kn = (kt + 1) * 64;
#pragma unroll
      for (int i = 0; i < 4; i++) {
        async_copy16(pa[i] + kn, &As[cur ^ 1][(w * 32 + i * 8) * 64]);
        async_copy16(pb[i] + kn, &Bs[cur ^ 1][(w * 32 + i * 8) * 64]);
      }
    }
#pragma unroll
    for (int kq = 0; kq < 64; kq += 32) {
      bf16x8 af[4], bf[4];
#pragma unroll
      for (int mi = 0; mi < 4; mi++)
        af[mi] = __builtin_bit_cast(bf16x8, *(const u16x8*)&As[cur][(am + mi * 16 + l16) * 64 + kq + quad * 8]);
#pragma unroll
      for (int ni = 0; ni < 4; ni++)
        bf[ni] = __builtin_bit_cast(bf16x8, *(const u16x8*)&Bs[cur][(bn + ni * 16 + l16) * 64 + kq + quad * 8]);
#pragma unroll
      for (int mi = 0; mi < 4; mi++)
#pragma unroll
        for (int ni = 0; ni < 4; ni++)
          acc[mi][ni] = __builtin_amdgcn_mfma_f32_16x16x32_bf16(af[mi], bf[ni], acc[mi][ni], 0, 0, 0);
    }
  }

#pragma unroll
  for (int mi = 0; mi < 4; mi++) {
    const int rgb = m0 + am + mi * 16 + quad * 4;
#pragma unroll
    for (int ni = 0; ni < 4; ni++) {
      const int gcol = n0 + bn + ni * 16 + l16;
      const float bias_v = bias[gcol];
#pragma unroll
      for (int r = 0; r < 4; r++) {
        int rg = rgb + r;
        if (rg < MROWS) out[(size_t)rg * HID + gcol] = acc[mi][ni][r] + bias_v;
      }
    }
  }
}

// ---------------------------------------------------------------------------
extern "C" void kernel_launch(void* const* d_in, const int* in_sizes, int n_in,
                              void* d_out, int out_size, void* d_ws, size_t ws_size,
                              hipStream_t stream) {
  const float* A[18];
  if (in_sizes[0] == HID * HID) {
    for (int i = 0; i < 18; i++) A[i] = (const float*)d_in[i];
  } else {
    A[16] = (const float*)d_in[0];
    A[17] = (const float*)d_in[1];
    for (int i = 0; i < 16; i++) A[i] = (const float*)d_in[i + 2];
  }
  const float *Wq = A[0], *bq = A[1], *Wk = A[2], *bk = A[3], *Wv = A[4], *bv = A[5];
  const float *Wqa = A[6], *bqa = A[7], *Wka = A[8], *bka = A[9], *Wva = A[10], *bva = A[11];
  const float *Wp = A[12], *bp = A[13], *Wpa = A[14], *bpa = A[15];
  const float *video = A[16], *action = A[17];
  float* out = (float*)d_out;

  const size_t qkv_elems = (size_t)BSZ * NHEAD * NTOK * HDIM;  // 4,227,072
  unsigned short* Wb  = (unsigned short*)d_ws;                  // 8 x 1M bf16
  unsigned short* Xb  = Wb + (size_t)8 * WSZ;                   // 4128 x 1024
  unsigned short* Qw  = Xb + (size_t)MROWS * HID;
  unsigned short* Kw  = Qw + qkv_elems;
  unsigned short* Vtw = Kw + qkv_elems;                         // (B,H,D,NTOK)
  unsigned short* ctx = Vtw + qkv_elems;                        // 4128 x 1024 bf16

  dim3 g0(512, 13);
  cvt_kernel<<<g0, 256, 0, stream>>>(Wq, Wk, Wv, Wqa, Wka, Wva, Wp, Wpa,
                                     video, action, Wb, Xb);
  dim3 g1(16, 33);
  qkvf_kernel<<<g1, 256, 0, stream>>>(Xb, Wb, bq, bk, bv, bqa, bka, bva,
                                      Qw, Kw, Vtw);
  dim3 g2(33, BSZ * NHEAD);
  attn_kernel<<<g2, 256, 0, stream>>>(Qw, Kw, Vtw, ctx);
  dim3 g3(8, 33);
  proj128_kernel<<<g3, 256, 0, stream>>>(ctx, Wb, bp, bpa, out);
}

// Round 6
// 359.285 us; speedup vs baseline: 1.0773x; 1.0593x over previous
//
#include <hip/hip_runtime.h>
#include <stdint.h>

#define HID   1024
#define NHEAD 16
#define HDIM  64
#define NV    2048
#define NA    16
#define NTOK  2064
#define BSZ   2
#define MROWS 4128    // 4096 video + 32 action (valid rows)
#define MPAD  4224    // padded to 33*128 for tile loads (rows 4128+ garbage, masked)
#define WSZ   1048576
// p = exp2(s * SCALE * log2(e) - 16)   [fixed-max softmax, exact after divide]
#define EXP_C1 0.18033688011112042f
#define EXP_C2 16.0f

// fragment-packed offsets: element (row r, col k) of a (16-row x 32-col) MFMA
// fragment tile stored lane-linear: lane = quad*16 + r15 reads 8 consecutive k.
#define POFF(r,k)  (((((r)>>4)*32  + ((k)>>5))*512) + ((((k)>>3)&3)*128) + (((r)&15)*8) + ((k)&7))   // 1024-col mats
#define QOFF(t,d)  (((((t)>>4)*2   + ((d)>>5))*512) + ((((d)>>3)&3)*128) + (((t)&15)*8) + ((d)&7))   // Q/K planes (64 col)
#define VOFF(d,ky) (((((d)>>4)*65  + ((ky)>>5))*512) + ((((ky)>>3)&3)*128) + (((d)&15)*8) + ((ky)&7)) // V^T planes (2080 keys padded)
#define QPLANE (129*2*512)    // 132096 elems per (b,h)
#define VPLANE (4*65*512)     // 133120 elems per (b,h)

typedef __bf16 bf16x8 __attribute__((ext_vector_type(8)));
typedef unsigned short u16x8 __attribute__((ext_vector_type(8)));
typedef unsigned short u16x4 __attribute__((ext_vector_type(4)));
typedef float f32x4 __attribute__((ext_vector_type(4)));

__device__ __forceinline__ unsigned short f2bf(float f) {  // RNE
  unsigned u = __builtin_bit_cast(unsigned, f);
  u += 0x7FFFu + ((u >> 16) & 1u);
  return (unsigned short)(u >> 16);
}
__device__ __forceinline__ float bf2f_trunc_inv(unsigned short h) {
  unsigned u = ((unsigned)h) << 16; return __builtin_bit_cast(float, u);
}
__device__ __forceinline__ unsigned short f2bf_trunc(float f) {
  return (unsigned short)(__builtin_bit_cast(unsigned, f) >> 16);
}
__device__ __forceinline__ bf16x8 ldfrag(const unsigned short* p) {
  return __builtin_bit_cast(bf16x8, *(const u16x8*)p);
}

// ---------------------------------------------------------------------------
// Kernel 0: fp32 -> bf16 convert + fragment-pack.
// Wb = [Wq,Wk,Wv,Wqa,Wka,Wva,Wp,Wpa] frag-packed; Xp = video||action packed.
// ---------------------------------------------------------------------------
__global__ __launch_bounds__(256) void cvt_kernel(
    const float* __restrict__ W0, const float* __restrict__ W1,
    const float* __restrict__ W2, const float* __restrict__ W3,
    const float* __restrict__ W4, const float* __restrict__ W5,
    const float* __restrict__ W6, const float* __restrict__ W7,
    const float* __restrict__ video, const float* __restrict__ action,
    unsigned short* __restrict__ Wb, unsigned short* __restrict__ Xp)
{
  const int y = blockIdx.y;
  const size_t idx = ((size_t)blockIdx.x * 256 + threadIdx.x) * 8;
  const float* src; unsigned short* dstbase; int row;
  if (y < 8) {
    const float* Ws[8] = {W0, W1, W2, W3, W4, W5, W6, W7};
    src = Ws[y] + idx; dstbase = Wb + (size_t)y * WSZ; row = (int)(idx >> 10);
  } else if (y < 12) {
    src = video + (size_t)(y - 8) * WSZ + idx; dstbase = Xp;
    row = ((y - 8) << 10) + (int)(idx >> 10);
  } else {
    if (idx >= (size_t)BSZ * NA * HID) return;
    src = action + idx; dstbase = Xp; row = 4096 + (int)(idx >> 10);
  }
  const int k0 = (int)(idx & 1023);
  float4 f0 = *(const float4*)src;
  float4 f1 = *(const float4*)(src + 4);
  u16x8 v;
  v[0]=f2bf(f0.x); v[1]=f2bf(f0.y); v[2]=f2bf(f0.z); v[3]=f2bf(f0.w);
  v[4]=f2bf(f1.x); v[5]=f2bf(f1.y); v[6]=f2bf(f1.z); v[7]=f2bf(f1.w);
  *(u16x8*)(dstbase + POFF(row, k0)) = v;
}

// row -> (batch, token) in the joint token space
__device__ __forceinline__ void row2bt(int rg, int& b, int& tok, bool& valid) {
  if (rg < 4096) { b = rg >> 11; tok = rg & 2047; valid = true; }
  else { int t = rg - 4096; b = t >> 4; tok = 2048 + (t & 15); valid = rg < MROWS; }
}

// ---------------------------------------------------------------------------
// Kernel 1: QKV GEMM — barrier-free, LDS-free, register fragments.
// grid (8 n-tiles, 33 m-tiles, 3 z); block 256 = 2x2 waves of 64x64.
// Epilogue: bias + RoPE; Q,K -> frag-packed (b,h) planes; V -> packed V^T.
// ---------------------------------------------------------------------------
__global__ __launch_bounds__(256) void qkv_kernel(
    const unsigned short* __restrict__ Xp, const unsigned short* __restrict__ Wb,
    const float* __restrict__ bq, const float* __restrict__ bk,
    const float* __restrict__ bv, const float* __restrict__ bqa,
    const float* __restrict__ bka, const float* __restrict__ bva,
    unsigned short* __restrict__ Qpk, unsigned short* __restrict__ Kpk,
    unsigned short* __restrict__ Vpk)
{
  const int tid  = threadIdx.x;
  const int w    = tid >> 6;
  const int lane = tid & 63;
  const int quad = lane >> 4;
  const int l16  = lane & 15;
  const int z    = blockIdx.z;
  const int m0   = blockIdx.y * 128;
  const int n0   = blockIdx.x * 128;
  const bool atile = (blockIdx.y == 32);

  const unsigned short* Wz = Wb + (size_t)(atile ? 3 + z : z) * WSZ;
  const float* bias = (z == 0) ? (atile ? bqa : bq)
                    : (z == 1) ? (atile ? bka : bk)
                               : (atile ? bva : bv);

  const int am = (w & 1) * 64;
  const int bn = (w >> 1) * 64;
  const int Mt = (m0 >> 4) + (am >> 4);   // row-tile base for this wave
  const int Nt = (n0 >> 4) + (bn >> 4);

  const unsigned short* pa = Xp + (size_t)Mt * 32 * 512 + lane * 8;
  const unsigned short* pb = Wz + (size_t)Nt * 32 * 512 + lane * 8;

  f32x4 acc[4][4] = {};

#pragma unroll 2
  for (int kt = 0; kt < 32; kt++) {
    bf16x8 af[4], bf[4];
#pragma unroll
    for (int mi = 0; mi < 4; mi++) af[mi] = ldfrag(pa + (size_t)(mi * 32 + kt) * 512);
#pragma unroll
    for (int ni = 0; ni < 4; ni++) bf[ni] = ldfrag(pb + (size_t)(ni * 32 + kt) * 512);
#pragma unroll
    for (int mi = 0; mi < 4; mi++)
#pragma unroll
      for (int ni = 0; ni < 4; ni++)
        acc[mi][ni] = __builtin_amdgcn_mfma_f32_16x16x32_bf16(af[mi], bf[ni], acc[mi][ni], 0, 0, 0);
  }

  if (z < 2) {
    unsigned short* O = (z == 0) ? Qpk : Kpk;
#pragma unroll
    for (int mi = 0; mi < 4; mi++) {
      const int rgb = m0 + am + mi * 16 + quad * 4;
#pragma unroll
      for (int ni = 0; ni < 4; ni++) {
        const int gcol = n0 + bn + ni * 16 + l16;
        const int head = gcol >> 6, col = gcol & 63;
        const float bias_v = bias[gcol];
        const int seg = (col >= 40) ? 2 : (col >= 20) ? 1 : 0;
        const int tin = col - seg * 20;
        const float om = exp2f(-(float)(tin >> 1) * 1.3287712379549449f);
        const bool evn = !(tin & 1);
#pragma unroll
        for (int r = 0; r < 4; r++) {
          int rg = rgb + r;
          int b, tok; bool valid;
          row2bt(rg, b, tok, valid);
          float val = acc[mi][ni][r] + bias_v;
          float part = __shfl_xor(val, 1);
          if (tok < 2048 && col < 60) {
            int dp = tok >> 8, hp = (tok >> 4) & 15, wp = tok & 15;
            float pos = (seg == 0) ? (float)dp : (seg == 1) ? (float)hp : (float)wp;
            float fr = pos * om;
            float cs = cosf(fr), sn = sinf(fr);
            val = evn ? (val * cs - part * sn) : (val * cs + part * sn);
          }
          if (valid)
            O[(size_t)(b * NHEAD + head) * QPLANE + QOFF(tok, col)] = f2bf(val);
        }
      }
    }
  } else {
#pragma unroll
    for (int mi = 0; mi < 4; mi++) {
      const int rgb = m0 + am + mi * 16 + quad * 4;
      int b, tok; bool valid;
      row2bt(rgb, b, tok, valid);
#pragma unroll
      for (int ni = 0; ni < 4; ni++) {
        const int gcol = n0 + bn + ni * 16 + l16;
        const int head = gcol >> 6, d = gcol & 63;
        const float bias_v = bias[gcol];
        u16x4 pk;
#pragma unroll
        for (int r = 0; r < 4; r++) pk[r] = f2bf(acc[z >= 2 ? 0 : 0, mi][ni][r] + bias_v);
        if (valid)
          *(u16x4*)&Vpk[(size_t)(b * NHEAD + head) * VPLANE + VOFF(d, tok)] = pk;
      }
    }
  }
}

// ---------------------------------------------------------------------------
// Kernel 2: flash attention — barrier-free. All operands loaded as register
// fragments from frag-packed planes. Only LDS: wave-private Ps (C->A of P).
// grid (33 q-tiles, B*H); block 256 (wave owns 16 q-rows).
// ---------------------------------------------------------------------------
__global__ __launch_bounds__(256) void attn_kernel(
    const unsigned short* __restrict__ Qpk,
    const unsigned short* __restrict__ Kpk,
    const unsigned short* __restrict__ Vpk,
    unsigned short* __restrict__ ctxp)
{
  __shared__ unsigned short Ps[4][16][68];

  const int tid  = threadIdx.x;
  const int wave = tid >> 6;
  const int lane = tid & 63;
  const int quad = lane >> 4;
  const int l16  = lane & 15;
  const int bh   = blockIdx.y;
  const int q0   = blockIdx.x * 64;
  const unsigned short* Qp = Qpk + (size_t)bh * QPLANE + lane * 8;
  const unsigned short* Kp = Kpk + (size_t)bh * QPLANE + lane * 8;
  const unsigned short* Vp = Vpk + (size_t)bh * VPLANE + lane * 8;

  // Q fragments for this wave's 16 rows (clamped for the padded last tile)
  const int qt = min((q0 >> 4) + wave, 128);
  bf16x8 aq[2];
#pragma unroll
  for (int c = 0; c < 2; c++) aq[c] = ldfrag(Qp + (size_t)(qt * 2 + c) * 512);

  u16x8 ones_u;
#pragma unroll
  for (int i = 0; i < 8; i++) ones_u[i] = 0x3F80;
  const bf16x8 ones = __builtin_bit_cast(bf16x8, ones_u);

  f32x4 oacc[4] = {};
  f32x4 lacc = {};

  for (int it = 0; it < 32; it++) {
    // S = Q K^T  (keys it*64 .. +64)
    f32x4 sacc[4] = {};
#pragma unroll
    for (int nt = 0; nt < 4; nt++) {
#pragma unroll
      for (int c = 0; c < 2; c++) {
        bf16x8 bk = ldfrag(Kp + (size_t)((it * 4 + nt) * 2 + c) * 512);
        sacc[nt] = __builtin_amdgcn_mfma_f32_16x16x32_bf16(aq[c], bk, sacc[nt], 0, 0, 0);
      }
    }
    // p = exp2(s*C1 - C2) -> wave-private Ps (C-layout -> A-layout)
#pragma unroll
    for (int nt = 0; nt < 4; nt++)
#pragma unroll
      for (int rr = 0; rr < 4; rr++)
        Ps[wave][quad * 4 + rr][nt * 16 + l16] =
            f2bf_trunc(exp2f(__builtin_fmaf(sacc[nt][rr], EXP_C1, -EXP_C2)));

    // O += P V ; l += P @ ones
#pragma unroll
    for (int c = 0; c < 2; c++) {
      u16x4 alo = *(const u16x4*)&Ps[wave][l16][c * 32 + quad * 8];
      u16x4 ahi = *(const u16x4*)&Ps[wave][l16][c * 32 + quad * 8 + 4];
      bf16x8 ap = __builtin_bit_cast(bf16x8,
          __builtin_shufflevector(alo, ahi, 0, 1, 2, 3, 4, 5, 6, 7));
#pragma unroll
      for (int nt = 0; nt < 4; nt++) {
        bf16x8 bv = ldfrag(Vp + (size_t)(nt * 65 + it * 2 + c) * 512);
        oacc[nt] = __builtin_amdgcn_mfma_f32_16x16x32_bf16(ap, bv, oacc[nt], 0, 0, 0);
      }
      lacc = __builtin_amdgcn_mfma_f32_16x16x32_bf16(ap, ones, lacc, 0, 0, 0);
    }
  }

  // ---- tail: keys 2048..2063 (keytile 128; V pad keys 2064..2079 killed by P=0)
  {
    f32x4 s0 = {};
#pragma unroll
    for (int c = 0; c < 2; c++) {
      bf16x8 bk = ldfrag(Kp + (size_t)(128 * 2 + c) * 512);
      s0 = __builtin_amdgcn_mfma_f32_16x16x32_bf16(aq[c], bk, s0, 0, 0, 0);
    }
#pragma unroll
    for (int rr = 0; rr < 4; rr++) {
      Ps[wave][quad * 4 + rr][l16]      = f2bf_trunc(exp2f(__builtin_fmaf(s0[rr], EXP_C1, -EXP_C2)));
      Ps[wave][quad * 4 + rr][16 + l16] = 0;
    }
    u16x4 alo = *(const u16x4*)&Ps[wave][l16][quad * 8];
    u16x4 ahi = *(const u16x4*)&Ps[wave][l16][quad * 8 + 4];
    bf16x8 ap = __builtin_bit_cast(bf16x8,
        __builtin_shufflevector(alo, ahi, 0, 1, 2, 3, 4, 5, 6, 7));
#pragma unroll
    for (int nt = 0; nt < 4; nt++) {
      bf16x8 bv = ldfrag(Vp + (size_t)(nt * 65 + 64) * 512);
      oacc[nt] = __builtin_amdgcn_mfma_f32_16x16x32_bf16(ap, bv, oacc[nt], 0, 0, 0);
    }
    lacc = __builtin_amdgcn_mfma_f32_16x16x32_bf16(ap, ones, lacc, 0, 0, 0);
  }

  const int b = bh >> 4, h = bh & 15;
  float rl[4];
#pragma unroll
  for (int rr = 0; rr < 4; rr++) rl[rr] = 1.f / lacc[rr];
#pragma unroll
  for (int nt = 0; nt < 4; nt++) {
#pragma unroll
    for (int rr = 0; rr < 4; rr++) {
      int token = q0 + wave * 16 + quad * 4 + rr;
      if (token < NTOK) {
        int row = (token < 2048) ? (b * 2048 + token) : (4096 + b * NA + (token - 2048));
        int col = h * HDIM + nt * 16 + l16;
        ctxp[POFF(row, col)] = f2bf(oacc[nt][rr] * rl[rr]);
      }
    }
  }
}

// ---------------------------------------------------------------------------
// Kernel 3: output projection — barrier-free reg-fragment GEMM from packed ctx.
// grid (8 n-tiles, 33 m-tiles); writes fp32 d_out (row-linear video||action).
// ---------------------------------------------------------------------------
__global__ __launch_bounds__(256) void proj_kernel(
    const unsigned short* __restrict__ ctxp, const unsigned short* __restrict__ Wb,
    const float* __restrict__ bp, const float* __restrict__ bpa,
    float* __restrict__ out)
{
  const int tid  = threadIdx.x;
  const int w    = tid >> 6;
  const int lane = tid & 63;
  const int quad = lane >> 4;
  const int l16  = lane & 15;
  const int m0   = blockIdx.y * 128;
  const int n0   = blockIdx.x * 128;
  const bool atile = (blockIdx.y == 32);

  const unsigned short* Wz = Wb + (size_t)(atile ? 7 : 6) * WSZ;
  const float* bias = atile ? bpa : bp;

  const int am = (w & 1) * 64;
  const int bn = (w >> 1) * 64;
  const int Mt = (m0 >> 4) + (am >> 4);
  const int Nt = (n0 >> 4) + (bn >> 4);

  const unsigned short* pa = ctxp + (size_t)Mt * 32 * 512 + lane * 8;
  const unsigned short* pb = Wz + (size_t)Nt * 32 * 512 + lane * 8;

  f32x4 acc[4][4] = {};

#pragma unroll 2
  for (int kt = 0; kt < 32; kt++) {
    bf16x8 af[4], bf[4];
#pragma unroll
    for (int mi = 0; mi < 4; mi++) af[mi] = ldfrag(pa + (size_t)(mi * 32 + kt) * 512);
#pragma unroll
    for (int ni = 0; ni < 4; ni++) bf[ni] = ldfrag(pb + (size_t)(ni * 32 + kt) * 512);
#pragma unroll
    for (int mi = 0; mi < 4; mi++)
#pragma unroll
      for (int ni = 0; ni < 4; ni++)
        acc[mi][ni] = __builtin_amdgcn_mfma_f32_16x16x32_bf16(af[mi], bf[ni], acc[mi][ni], 0, 0, 0);
  }

#pragma unroll
  for (int mi = 0; mi < 4; mi++) {
    const int rgb = m0 + am + mi * 16 + quad * 4;
#pragma unroll
    for (int ni = 0; ni < 4; ni++) {
      const int gcol = n0 + bn + ni * 16 + l16;
      const float bias_v = bias[gcol];
#pragma unroll
      for (int r = 0; r < 4; r++) {
        int rg = rgb + r;
        if (rg < MROWS) out[(size_t)rg * HID + gcol] = acc[mi][ni][r] + bias_v;
      }
    }
  }
}

// ---------------------------------------------------------------------------
extern "C" void kernel_launch(void* const* d_in, const int* in_sizes, int n_in,
                              void* d_out, int out_size, void* d_ws, size_t ws_size,
                              hipStream_t stream) {
  const float* A[18];
  if (in_sizes[0] == HID * HID) {
    for (int i = 0; i < 18; i++) A[i] = (const float*)d_in[i];
  } else {
    A[16] = (const float*)d_in[0];
    A[17] = (const float*)d_in[1];
    for (int i = 0; i < 16; i++) A[i] = (const float*)d_in[i + 2];
  }
  const float *Wq = A[0], *bq = A[1], *Wk = A[2], *bk = A[3], *Wv = A[4], *bv = A[5];
  const float *Wqa = A[6], *bqa = A[7], *Wka = A[8], *bka = A[9], *Wva = A[10], *bva = A[11];
  const float *Wp = A[12], *bp = A[13], *Wpa = A[14], *bpa = A[15];
  const float *video = A[16], *action = A[17];
  float* out = (float*)d_out;

  unsigned short* Wb   = (unsigned short*)d_ws;                 // 8 x 1M packed
  unsigned short* Xp   = Wb + (size_t)8 * WSZ;                  // MPAD x 1024 packed
  unsigned short* Qpk  = Xp + (size_t)(MPAD / 16) * 32 * 512;   // 32 planes
  unsigned short* Kpk  = Qpk + (size_t)32 * QPLANE;
  unsigned short* Vpk  = Kpk + (size_t)32 * QPLANE;
  unsigned short* ctxp = Vpk + (size_t)32 * VPLANE;             // MPAD x 1024 packed

  dim3 g0(512, 13);
  cvt_kernel<<<g0, 256, 0, stream>>>(Wq, Wk, Wv, Wqa, Wka, Wva, Wp, Wpa,
                                     video, action, Wb, Xp);
  dim3 g1(8, 33, 3);
  qkv_kernel<<<g1, 256, 0, stream>>>(Xp, Wb, bq, bk, bv, bqa, bka, bva,
                                     Qpk, Kpk, Vpk);
  dim3 g2(33, BSZ * NHEAD);
  attn_kernel<<<g2, 256, 0, stream>>>(Qpk, Kpk, Vpk, ctxp);
  dim3 g3(8, 33);
  proj_kernel<<<g3, 256, 0, stream>>>(ctxp, Wb, bp, bpa, out);
}

// Round 7
// 323.957 us; speedup vs baseline: 1.1948x; 1.1091x over previous
//
#include <hip/hip_runtime.h>
#include <stdint.h>

#define HID   1024
#define NHEAD 16
#define HDIM  64
#define NV    2048
#define NA    16
#define NTOK  2064
#define BSZ   2
#define MROWS 4128    // 4096 video + 32 action (valid rows)
#define MPAD  4224    // padded to 33*128 (rows 4128+ garbage, masked on output)
#define WSZ   1048576
// p = exp2(s * SCALE * log2(e) - 16)   [fixed-max softmax, exact after divide]
#define EXP_C1 0.18033688011112042f
#define EXP_C2 16.0f

// fragment-packed offsets: element (row r, col k) of a (16-row x 32-col) MFMA
// fragment tile stored lane-linear: lane = quad*16 + r15 reads 8 consecutive k.
#define POFF(r,k)  (((((r)>>4)*32  + ((k)>>5))*512) + ((((k)>>3)&3)*128) + (((r)&15)*8) + ((k)&7))   // 1024-col mats
#define QOFF(t,d)  (((((t)>>4)*2   + ((d)>>5))*512) + ((((d)>>3)&3)*128) + (((t)&15)*8) + ((d)&7))   // Q/K planes (64 col)
#define VOFF(d,ky) (((((d)>>4)*65  + ((ky)>>5))*512) + ((((ky)>>3)&3)*128) + (((d)&15)*8) + ((ky)&7)) // V^T planes (2080 keys padded)
#define QPLANE (129*2*512)    // 132096 elems per (b,h)
#define VPLANE (4*65*512)     // 133120 elems per (b,h)

typedef __bf16 bf16x8 __attribute__((ext_vector_type(8)));
typedef unsigned short u16x8 __attribute__((ext_vector_type(8)));
typedef unsigned short u16x4 __attribute__((ext_vector_type(4)));
typedef float f32x4 __attribute__((ext_vector_type(4)));

__device__ __forceinline__ unsigned short f2bf(float f) {  // RNE
  unsigned u = __builtin_bit_cast(unsigned, f);
  u += 0x7FFFu + ((u >> 16) & 1u);
  return (unsigned short)(u >> 16);
}
__device__ __forceinline__ unsigned short f2bf_trunc(float f) {
  return (unsigned short)(__builtin_bit_cast(unsigned, f) >> 16);
}
__device__ __forceinline__ bf16x8 ldfrag(const unsigned short* p) {
  return __builtin_bit_cast(bf16x8, *(const u16x8*)p);
}

// ---------------------------------------------------------------------------
// Kernel 0: fp32 -> bf16 convert + fragment-pack.
// ---------------------------------------------------------------------------
__global__ __launch_bounds__(256) void cvt_kernel(
    const float* __restrict__ W0, const float* __restrict__ W1,
    const float* __restrict__ W2, const float* __restrict__ W3,
    const float* __restrict__ W4, const float* __restrict__ W5,
    const float* __restrict__ W6, const float* __restrict__ W7,
    const float* __restrict__ video, const float* __restrict__ action,
    unsigned short* __restrict__ Wb, unsigned short* __restrict__ Xp)
{
  const int y = blockIdx.y;
  const size_t idx = ((size_t)blockIdx.x * 256 + threadIdx.x) * 8;
  const float* src; unsigned short* dstbase; int row;
  if (y < 8) {
    const float* Ws[8] = {W0, W1, W2, W3, W4, W5, W6, W7};
    src = Ws[y] + idx; dstbase = Wb + (size_t)y * WSZ; row = (int)(idx >> 10);
  } else if (y < 12) {
    src = video + (size_t)(y - 8) * WSZ + idx; dstbase = Xp;
    row = ((y - 8) << 10) + (int)(idx >> 10);
  } else {
    if (idx >= (size_t)BSZ * NA * HID) return;
    src = action + idx; dstbase = Xp; row = 4096 + (int)(idx >> 10);
  }
  const int k0 = (int)(idx & 1023);
  float4 f0 = *(const float4*)src;
  float4 f1 = *(const float4*)(src + 4);
  u16x8 v;
  v[0]=f2bf(f0.x); v[1]=f2bf(f0.y); v[2]=f2bf(f0.z); v[3]=f2bf(f0.w);
  v[4]=f2bf(f1.x); v[5]=f2bf(f1.y); v[6]=f2bf(f1.z); v[7]=f2bf(f1.w);
  *(u16x8*)(dstbase + POFF(row, k0)) = v;
}

// row -> (batch, token) in the joint token space
__device__ __forceinline__ void row2bt(int rg, int& b, int& tok, bool& valid) {
  if (rg < 4096) { b = rg >> 11; tok = rg & 2047; valid = true; }
  else { int t = rg - 4096; b = t >> 4; tok = 2048 + (t & 15); valid = rg < MROWS; }
}

// ---------------------------------------------------------------------------
// Kernel 1: QKV GEMM — barrier/LDS-free reg-fragment GEMM, 512-thr blocks.
// grid (8 n, 3 z, 33 m); block = 8 waves, wave = 32m x 64n (acc[2][4]).
// Explicit 2-stage register double-buffer on the fragment loads.
// ---------------------------------------------------------------------------
__global__ __launch_bounds__(512) void qkv_kernel(
    const unsigned short* __restrict__ Xp, const unsigned short* __restrict__ Wb,
    const float* __restrict__ bq, const float* __restrict__ bk,
    const float* __restrict__ bv, const float* __restrict__ bqa,
    const float* __restrict__ bka, const float* __restrict__ bva,
    unsigned short* __restrict__ Qpk, unsigned short* __restrict__ Kpk,
    unsigned short* __restrict__ Vpk)
{
  const int tid  = threadIdx.x;
  const int w    = tid >> 6;
  const int lane = tid & 63;
  const int quad = lane >> 4;
  const int l16  = lane & 15;
  const int mh   = w & 3;        // m quarter (32 rows)
  const int nh   = w >> 2;       // n half (64 cols)
  const int n0   = blockIdx.x * 128;
  const int z    = blockIdx.y;
  const int m0   = blockIdx.z * 128;
  const bool atile = (blockIdx.z == 32);

  const unsigned short* Wz = Wb + (size_t)(atile ? 3 + z : z) * WSZ;
  const float* bias = (z == 0) ? (atile ? bqa : bq)
                    : (z == 1) ? (atile ? bka : bk)
                               : (atile ? bva : bv);

  const int Mt = (m0 >> 4) + mh * 2;
  const int Nt = (n0 >> 4) + nh * 4;
  const unsigned short* pa = Xp + (size_t)Mt * 32 * 512 + lane * 8;
  const unsigned short* pb = Wz + (size_t)Nt * 32 * 512 + lane * 8;

  f32x4 acc[2][4] = {};
  bf16x8 af[2][2], bf[2][4];

#pragma unroll
  for (int mi = 0; mi < 2; mi++) af[0][mi] = ldfrag(pa + (size_t)(mi * 32) * 512);
#pragma unroll
  for (int ni = 0; ni < 4; ni++) bf[0][ni] = ldfrag(pb + (size_t)(ni * 32) * 512);

  for (int kt = 0; kt < 32; kt++) {
    const int cb = kt & 1, nb = cb ^ 1;
    if (kt < 31) {
#pragma unroll
      for (int mi = 0; mi < 2; mi++) af[nb][mi] = ldfrag(pa + (size_t)(mi * 32 + kt + 1) * 512);
#pragma unroll
      for (int ni = 0; ni < 4; ni++) bf[nb][ni] = ldfrag(pb + (size_t)(ni * 32 + kt + 1) * 512);
    }
#pragma unroll
    for (int mi = 0; mi < 2; mi++)
#pragma unroll
      for (int ni = 0; ni < 4; ni++)
        acc[mi][ni] = __builtin_amdgcn_mfma_f32_16x16x32_bf16(af[cb][mi], bf[cb][ni], acc[mi][ni], 0, 0, 0);
  }

  if (z < 2) {
    unsigned short* O = (z == 0) ? Qpk : Kpk;
#pragma unroll
    for (int mi = 0; mi < 2; mi++) {
      const int rgb = m0 + mh * 32 + mi * 16 + quad * 4;
#pragma unroll
      for (int ni = 0; ni < 4; ni++) {
        const int gcol = n0 + nh * 64 + ni * 16 + l16;
        const int head = gcol >> 6, col = gcol & 63;
        const float bias_v = bias[gcol];
        const int seg = (col >= 40) ? 2 : (col >= 20) ? 1 : 0;
        const int tin = col - seg * 20;
        const float om = exp2f(-(float)(tin >> 1) * 1.3287712379549449f);
        const bool evn = !(tin & 1);
#pragma unroll
        for (int r = 0; r < 4; r++) {
          int rg = rgb + r;
          int b, tok; bool valid;
          row2bt(rg, b, tok, valid);
          float val = acc[mi][ni][r] + bias_v;
          float part = __shfl_xor(val, 1);
          if (tok < 2048 && col < 60) {
            int dp = tok >> 8, hp = (tok >> 4) & 15, wp = tok & 15;
            float pos = (seg == 0) ? (float)dp : (seg == 1) ? (float)hp : (float)wp;
            float fr = pos * om;
            float cs = cosf(fr), sn = sinf(fr);
            val = evn ? (val * cs - part * sn) : (val * cs + part * sn);
          }
          if (valid)
            O[(size_t)(b * NHEAD + head) * QPLANE + QOFF(tok, col)] = f2bf(val);
        }
      }
    }
  } else {
#pragma unroll
    for (int mi = 0; mi < 2; mi++) {
      const int rgb = m0 + mh * 32 + mi * 16 + quad * 4;
      int b, tok; bool valid;
      row2bt(rgb, b, tok, valid);
#pragma unroll
      for (int ni = 0; ni < 4; ni++) {
        const int gcol = n0 + nh * 64 + ni * 16 + l16;
        const int head = gcol >> 6, d = gcol & 63;
        const float bias_v = bias[gcol];
        u16x4 pk;
#pragma unroll
        for (int r = 0; r < 4; r++) pk[r] = f2bf(acc[mi][ni][r] + bias_v);
        if (valid)
          *(u16x4*)&Vpk[(size_t)(b * NHEAD + head) * VPLANE + VOFF(d, tok)] = pk;
      }
    }
  }
}

// ---------------------------------------------------------------------------
// Kernel 2: flash attention — barrier-free reg-fragment (unchanged from R6).
// grid (33 q-tiles, B*H); block 256 (wave owns 16 q-rows).
// ---------------------------------------------------------------------------
__global__ __launch_bounds__(256) void attn_kernel(
    const unsigned short* __restrict__ Qpk,
    const unsigned short* __restrict__ Kpk,
    const unsigned short* __restrict__ Vpk,
    unsigned short* __restrict__ ctxp)
{
  __shared__ unsigned short Ps[4][16][68];

  const int tid  = threadIdx.x;
  const int wave = tid >> 6;
  const int lane = tid & 63;
  const int quad = lane >> 4;
  const int l16  = lane & 15;
  const int bh   = blockIdx.y;
  const int q0   = blockIdx.x * 64;
  const unsigned short* Qp = Qpk + (size_t)bh * QPLANE + lane * 8;
  const unsigned short* Kp = Kpk + (size_t)bh * QPLANE + lane * 8;
  const unsigned short* Vp = Vpk + (size_t)bh * VPLANE + lane * 8;

  const int qt = min((q0 >> 4) + wave, 128);
  bf16x8 aq[2];
#pragma unroll
  for (int c = 0; c < 2; c++) aq[c] = ldfrag(Qp + (size_t)(qt * 2 + c) * 512);

  u16x8 ones_u;
#pragma unroll
  for (int i = 0; i < 8; i++) ones_u[i] = 0x3F80;
  const bf16x8 ones = __builtin_bit_cast(bf16x8, ones_u);

  f32x4 oacc[4] = {};
  f32x4 lacc = {};

  for (int it = 0; it < 32; it++) {
    f32x4 sacc[4] = {};
#pragma unroll
    for (int nt = 0; nt < 4; nt++) {
#pragma unroll
      for (int c = 0; c < 2; c++) {
        bf16x8 bk = ldfrag(Kp + (size_t)((it * 4 + nt) * 2 + c) * 512);
        sacc[nt] = __builtin_amdgcn_mfma_f32_16x16x32_bf16(aq[c], bk, sacc[nt], 0, 0, 0);
      }
    }
#pragma unroll
    for (int nt = 0; nt < 4; nt++)
#pragma unroll
      for (int rr = 0; rr < 4; rr++)
        Ps[wave][quad * 4 + rr][nt * 16 + l16] =
            f2bf_trunc(exp2f(__builtin_fmaf(sacc[nt][rr], EXP_C1, -EXP_C2)));

#pragma unroll
    for (int c = 0; c < 2; c++) {
      u16x4 alo = *(const u16x4*)&Ps[wave][l16][c * 32 + quad * 8];
      u16x4 ahi = *(const u16x4*)&Ps[wave][l16][c * 32 + quad * 8 + 4];
      bf16x8 ap = __builtin_bit_cast(bf16x8,
          __builtin_shufflevector(alo, ahi, 0, 1, 2, 3, 4, 5, 6, 7));
#pragma unroll
      for (int nt = 0; nt < 4; nt++) {
        bf16x8 bv = ldfrag(Vp + (size_t)(nt * 65 + it * 2 + c) * 512);
        oacc[nt] = __builtin_amdgcn_mfma_f32_16x16x32_bf16(ap, bv, oacc[nt], 0, 0, 0);
      }
      lacc = __builtin_amdgcn_mfma_f32_16x16x32_bf16(ap, ones, lacc, 0, 0, 0);
    }
  }

  // tail: keys 2048..2063 (keytile 128; V pad keys killed by P=0)
  {
    f32x4 s0 = {};
#pragma unroll
    for (int c = 0; c < 2; c++) {
      bf16x8 bk = ldfrag(Kp + (size_t)(128 * 2 + c) * 512);
      s0 = __builtin_amdgcn_mfma_f32_16x16x32_bf16(aq[c], bk, s0, 0, 0, 0);
    }
#pragma unroll
    for (int rr = 0; rr < 4; rr++) {
      Ps[wave][quad * 4 + rr][l16]      = f2bf_trunc(exp2f(__builtin_fmaf(s0[rr], EXP_C1, -EXP_C2)));
      Ps[wave][quad * 4 + rr][16 + l16] = 0;
    }
    u16x4 alo = *(const u16x4*)&Ps[wave][l16][quad * 8];
    u16x4 ahi = *(const u16x4*)&Ps[wave][l16][quad * 8 + 4];
    bf16x8 ap = __builtin_bit_cast(bf16x8,
        __builtin_shufflevector(alo, ahi, 0, 1, 2, 3, 4, 5, 6, 7));
#pragma unroll
    for (int nt = 0; nt < 4; nt++) {
      bf16x8 bv = ldfrag(Vp + (size_t)(nt * 65 + 64) * 512);
      oacc[nt] = __builtin_amdgcn_mfma_f32_16x16x32_bf16(ap, bv, oacc[nt], 0, 0, 0);
    }
    lacc = __builtin_amdgcn_mfma_f32_16x16x32_bf16(ap, ones, lacc, 0, 0, 0);
  }

  const int b = bh >> 4, h = bh & 15;
  float rl[4];
#pragma unroll
  for (int rr = 0; rr < 4; rr++) rl[rr] = 1.f / lacc[rr];
#pragma unroll
  for (int nt = 0; nt < 4; nt++) {
#pragma unroll
    for (int rr = 0; rr < 4; rr++) {
      int token = q0 + wave * 16 + quad * 4 + rr;
      if (token < NTOK) {
        int row = (token < 2048) ? (b * 2048 + token) : (4096 + b * NA + (token - 2048));
        int col = h * HDIM + nt * 16 + l16;
        ctxp[POFF(row, col)] = f2bf(oacc[nt][rr] * rl[rr]);
      }
    }
  }
}

// ---------------------------------------------------------------------------
// Kernel 3: output projection — 64x64 tiles, grid (16 n, 66 m) = 1056 blocks.
// Barrier-free reg-fragment GEMM with 2-stage prefetch; W slices L2-resident.
// ---------------------------------------------------------------------------
__global__ __launch_bounds__(256) void proj_kernel(
    const unsigned short* __restrict__ ctxp, const unsigned short* __restrict__ Wb,
    const float* __restrict__ bp, const float* __restrict__ bpa,
    float* __restrict__ out)
{
  const int tid  = threadIdx.x;
  const int w    = tid >> 6;
  const int lane = tid & 63;
  const int quad = lane >> 4;
  const int l16  = lane & 15;
  const int mh   = w & 1;        // 32-row half
  const int nh   = w >> 1;       // 32-col half
  const int m0   = blockIdx.y * 64;
  const int n0   = blockIdx.x * 64;
  const bool atile = (blockIdx.y >= 64);

  const unsigned short* Wz = Wb + (size_t)(atile ? 7 : 6) * WSZ;
  const float* bias = atile ? bpa : bp;

  const int Mt = (m0 >> 4) + mh * 2;
  const int Nt = (n0 >> 4) + nh * 2;
  const unsigned short* pa = ctxp + (size_t)Mt * 32 * 512 + lane * 8;
  const unsigned short* pb = Wz + (size_t)Nt * 32 * 512 + lane * 8;

  f32x4 acc[2][2] = {};
  bf16x8 af[2][2], bf[2][2];

#pragma unroll
  for (int mi = 0; mi < 2; mi++) af[0][mi] = ldfrag(pa + (size_t)(mi * 32) * 512);
#pragma unroll
  for (int ni = 0; ni < 2; ni++) bf[0][ni] = ldfrag(pb + (size_t)(ni * 32) * 512);

  for (int kt = 0; kt < 32; kt++) {
    const int cb = kt & 1, nb = cb ^ 1;
    if (kt < 31) {
#pragma unroll
      for (int mi = 0; mi < 2; mi++) af[nb][mi] = ldfrag(pa + (size_t)(mi * 32 + kt + 1) * 512);
#pragma unroll
      for (int ni = 0; ni < 2; ni++) bf[nb][ni] = ldfrag(pb + (size_t)(ni * 32 + kt + 1) * 512);
    }
#pragma unroll
    for (int mi = 0; mi < 2; mi++)
#pragma unroll
      for (int ni = 0; ni < 2; ni++)
        acc[mi][ni] = __builtin_amdgcn_mfma_f32_16x16x32_bf16(af[cb][mi], bf[cb][ni], acc[mi][ni], 0, 0, 0);
  }

#pragma unroll
  for (int mi = 0; mi < 2; mi++) {
    const int rgb = m0 + mh * 32 + mi * 16 + quad * 4;
#pragma unroll
    for (int ni = 0; ni < 2; ni++) {
      const int gcol = n0 + nh * 32 + ni * 16 + l16;
      const float bias_v = bias[gcol];
#pragma unroll
      for (int r = 0; r < 4; r++) {
        int rg = rgb + r;
        if (rg < MROWS) out[(size_t)rg * HID + gcol] = acc[mi][ni][r] + bias_v;
      }
    }
  }
}

// ---------------------------------------------------------------------------
extern "C" void kernel_launch(void* const* d_in, const int* in_sizes, int n_in,
                              void* d_out, int out_size, void* d_ws, size_t ws_size,
                              hipStream_t stream) {
  const float* A[18];
  if (in_sizes[0] == HID * HID) {
    for (int i = 0; i < 18; i++) A[i] = (const float*)d_in[i];
  } else {
    A[16] = (const float*)d_in[0];
    A[17] = (const float*)d_in[1];
    for (int i = 0; i < 16; i++) A[i] = (const float*)d_in[i + 2];
  }
  const float *Wq = A[0], *bq = A[1], *Wk = A[2], *bk = A[3], *Wv = A[4], *bv = A[5];
  const float *Wqa = A[6], *bqa = A[7], *Wka = A[8], *bka = A[9], *Wva = A[10], *bva = A[11];
  const float *Wp = A[12], *bp = A[13], *Wpa = A[14], *bpa = A[15];
  const float *video = A[16], *action = A[17];
  float* out = (float*)d_out;

  unsigned short* Wb   = (unsigned short*)d_ws;                 // 8 x 1M packed
  unsigned short* Xp   = Wb + (size_t)8 * WSZ;                  // MPAD x 1024 packed
  unsigned short* Qpk  = Xp + (size_t)(MPAD / 16) * 32 * 512;   // 32 planes
  unsigned short* Kpk  = Qpk + (size_t)32 * QPLANE;
  unsigned short* Vpk  = Kpk + (size_t)32 * QPLANE;
  unsigned short* ctxp = Vpk + (size_t)32 * VPLANE;             // MPAD x 1024 packed

  dim3 g0(512, 13);
  cvt_kernel<<<g0, 256, 0, stream>>>(Wq, Wk, Wv, Wqa, Wka, Wva, Wp, Wpa,
                                     video, action, Wb, Xp);
  dim3 g1(8, 3, 33);
  qkv_kernel<<<g1, 512, 0, stream>>>(Xp, Wb, bq, bk, bv, bqa, bka, bva,
                                     Qpk, Kpk, Vpk);
  dim3 g2(33, BSZ * NHEAD);
  attn_kernel<<<g2, 256, 0, stream>>>(Qpk, Kpk, Vpk, ctxp);
  dim3 g3(16, 66);
  proj_kernel<<<g3, 256, 0, stream>>>(ctxp, Wb, bp, bpa, out);
}

// Round 8
// 314.947 us; speedup vs baseline: 1.2290x; 1.0286x over previous
//
#include <hip/hip_runtime.h>
#include <stdint.h>

#define HID   1024
#define NHEAD 16
#define HDIM  64
#define NV    2048
#define NA    16
#define NTOK  2064
#define BSZ   2
#define MROWS 4128    // 4096 video + 32 action (valid rows)
#define MPAD  4224    // padded to 33*128 (rows 4128+ garbage, masked on output)
#define WSZ   1048576
// p = exp2(s * SCALE * log2(e) - 16)   [fixed-max softmax, exact after divide]
#define EXP_C1 0.18033688011112042f
#define EXP_C2 16.0f

// fragment-packed offsets: element (row r, col k) of a (16-row x 32-col) MFMA
// fragment tile stored lane-linear: lane = quad*16 + r15 reads 8 consecutive k.
#define POFF(r,k)  (((((r)>>4)*32  + ((k)>>5))*512) + ((((k)>>3)&3)*128) + (((r)&15)*8) + ((k)&7))   // 1024-col mats
#define QOFF(t,d)  (((((t)>>4)*2   + ((d)>>5))*512) + ((((d)>>3)&3)*128) + (((t)&15)*8) + ((d)&7))   // Q/K planes (64 col)
#define VOFF(d,ky) (((((d)>>4)*65  + ((ky)>>5))*512) + ((((ky)>>3)&3)*128) + (((d)&15)*8) + ((ky)&7)) // V^T planes (2080 keys padded)
#define QPLANE (129*2*512)    // 132096 elems per (b,h)
#define VPLANE (4*65*512)     // 133120 elems per (b,h)

typedef __bf16 bf16x8 __attribute__((ext_vector_type(8)));
typedef unsigned short u16x8 __attribute__((ext_vector_type(8)));
typedef unsigned short u16x4 __attribute__((ext_vector_type(4)));
typedef float f32x4 __attribute__((ext_vector_type(4)));

__device__ __forceinline__ unsigned short f2bf(float f) {  // RNE
  unsigned u = __builtin_bit_cast(unsigned, f);
  u += 0x7FFFu + ((u >> 16) & 1u);
  return (unsigned short)(u >> 16);
}
__device__ __forceinline__ unsigned short f2bf_trunc(float f) {
  return (unsigned short)(__builtin_bit_cast(unsigned, f) >> 16);
}
__device__ __forceinline__ bf16x8 ldfrag(const unsigned short* p) {
  return __builtin_bit_cast(bf16x8, *(const u16x8*)p);
}

// ---------------------------------------------------------------------------
// Kernel 0: fp32 -> bf16 convert + fragment-pack.
// ---------------------------------------------------------------------------
__global__ __launch_bounds__(256) void cvt_kernel(
    const float* __restrict__ W0, const float* __restrict__ W1,
    const float* __restrict__ W2, const float* __restrict__ W3,
    const float* __restrict__ W4, const float* __restrict__ W5,
    const float* __restrict__ W6, const float* __restrict__ W7,
    const float* __restrict__ video, const float* __restrict__ action,
    unsigned short* __restrict__ Wb, unsigned short* __restrict__ Xp)
{
  const int y = blockIdx.y;
  const size_t idx = ((size_t)blockIdx.x * 256 + threadIdx.x) * 8;
  const float* src; unsigned short* dstbase; int row;
  if (y < 8) {
    const float* Ws[8] = {W0, W1, W2, W3, W4, W5, W6, W7};
    src = Ws[y] + idx; dstbase = Wb + (size_t)y * WSZ; row = (int)(idx >> 10);
  } else if (y < 12) {
    src = video + (size_t)(y - 8) * WSZ + idx; dstbase = Xp;
    row = ((y - 8) << 10) + (int)(idx >> 10);
  } else {
    if (idx >= (size_t)BSZ * NA * HID) return;
    src = action + idx; dstbase = Xp; row = 4096 + (int)(idx >> 10);
  }
  const int k0 = (int)(idx & 1023);
  float4 f0 = *(const float4*)src;
  float4 f1 = *(const float4*)(src + 4);
  u16x8 v;
  v[0]=f2bf(f0.x); v[1]=f2bf(f0.y); v[2]=f2bf(f0.z); v[3]=f2bf(f0.w);
  v[4]=f2bf(f1.x); v[5]=f2bf(f1.y); v[6]=f2bf(f1.z); v[7]=f2bf(f1.w);
  *(u16x8*)(dstbase + POFF(row, k0)) = v;
}

// row -> (batch, token) in the joint token space
__device__ __forceinline__ void row2bt(int rg, int& b, int& tok, bool& valid) {
  if (rg < 4096) { b = rg >> 11; tok = rg & 2047; valid = true; }
  else { int t = rg - 4096; b = t >> 4; tok = 2048 + (t & 15); valid = rg < MROWS; }
}

// ---------------------------------------------------------------------------
// Kernel 1: QKV GEMM — barrier/LDS-free reg-fragment GEMM, 512-thr blocks.
// grid (8 n, 3 z, 33 m); block = 8 waves, wave = 32m x 64n (acc[2][4]).
// ---------------------------------------------------------------------------
__global__ __launch_bounds__(512) void qkv_kernel(
    const unsigned short* __restrict__ Xp, const unsigned short* __restrict__ Wb,
    const float* __restrict__ bq, const float* __restrict__ bk,
    const float* __restrict__ bv, const float* __restrict__ bqa,
    const float* __restrict__ bka, const float* __restrict__ bva,
    unsigned short* __restrict__ Qpk, unsigned short* __restrict__ Kpk,
    unsigned short* __restrict__ Vpk)
{
  const int tid  = threadIdx.x;
  const int w    = tid >> 6;
  const int lane = tid & 63;
  const int quad = lane >> 4;
  const int l16  = lane & 15;
  const int mh   = w & 3;        // m quarter (32 rows)
  const int nh   = w >> 2;       // n half (64 cols)
  const int n0   = blockIdx.x * 128;
  const int z    = blockIdx.y;
  const int m0   = blockIdx.z * 128;
  const bool atile = (blockIdx.z == 32);

  const unsigned short* Wz = Wb + (size_t)(atile ? 3 + z : z) * WSZ;
  const float* bias = (z == 0) ? (atile ? bqa : bq)
                    : (z == 1) ? (atile ? bka : bk)
                               : (atile ? bva : bv);

  const int Mt = (m0 >> 4) + mh * 2;
  const int Nt = (n0 >> 4) + nh * 4;
  const unsigned short* pa = Xp + (size_t)Mt * 32 * 512 + lane * 8;
  const unsigned short* pb = Wz + (size_t)Nt * 32 * 512 + lane * 8;

  f32x4 acc[2][4] = {};
  bf16x8 af[2][2], bf[2][4];

#pragma unroll
  for (int mi = 0; mi < 2; mi++) af[0][mi] = ldfrag(pa + (size_t)(mi * 32) * 512);
#pragma unroll
  for (int ni = 0; ni < 4; ni++) bf[0][ni] = ldfrag(pb + (size_t)(ni * 32) * 512);

  for (int kt = 0; kt < 32; kt++) {
    const int cb = kt & 1, nb = cb ^ 1;
    if (kt < 31) {
#pragma unroll
      for (int mi = 0; mi < 2; mi++) af[nb][mi] = ldfrag(pa + (size_t)(mi * 32 + kt + 1) * 512);
#pragma unroll
      for (int ni = 0; ni < 4; ni++) bf[nb][ni] = ldfrag(pb + (size_t)(ni * 32 + kt + 1) * 512);
    }
#pragma unroll
    for (int mi = 0; mi < 2; mi++)
#pragma unroll
      for (int ni = 0; ni < 4; ni++)
        acc[mi][ni] = __builtin_amdgcn_mfma_f32_16x16x32_bf16(af[cb][mi], bf[cb][ni], acc[mi][ni], 0, 0, 0);
  }

  if (z < 2) {
    unsigned short* O = (z == 0) ? Qpk : Kpk;
#pragma unroll
    for (int mi = 0; mi < 2; mi++) {
      const int rgb = m0 + mh * 32 + mi * 16 + quad * 4;
#pragma unroll
      for (int ni = 0; ni < 4; ni++) {
        const int gcol = n0 + nh * 64 + ni * 16 + l16;
        const int head = gcol >> 6, col = gcol & 63;
        const float bias_v = bias[gcol];
        const int seg = (col >= 40) ? 2 : (col >= 20) ? 1 : 0;
        const int tin = col - seg * 20;
        const float om = exp2f(-(float)(tin >> 1) * 1.3287712379549449f);
        const bool evn = !(tin & 1);
#pragma unroll
        for (int r = 0; r < 4; r++) {
          int rg = rgb + r;
          int b, tok; bool valid;
          row2bt(rg, b, tok, valid);
          float val = acc[mi][ni][r] + bias_v;
          float part = __shfl_xor(val, 1);
          if (tok < 2048 && col < 60) {
            int dp = tok >> 8, hp = (tok >> 4) & 15, wp = tok & 15;
            float pos = (seg == 0) ? (float)dp : (seg == 1) ? (float)hp : (float)wp;
            float fr = pos * om;
            float cs = cosf(fr), sn = sinf(fr);
            val = evn ? (val * cs - part * sn) : (val * cs + part * sn);
          }
          if (valid)
            O[(size_t)(b * NHEAD + head) * QPLANE + QOFF(tok, col)] = f2bf(val);
        }
      }
    }
  } else {
#pragma unroll
    for (int mi = 0; mi < 2; mi++) {
      const int rgb = m0 + mh * 32 + mi * 16 + quad * 4;
      int b, tok; bool valid;
      row2bt(rgb, b, tok, valid);
#pragma unroll
      for (int ni = 0; ni < 4; ni++) {
        const int gcol = n0 + nh * 64 + ni * 16 + l16;
        const int head = gcol >> 6, d = gcol & 63;
        const float bias_v = bias[gcol];
        u16x4 pk;
#pragma unroll
        for (int r = 0; r < 4; r++) pk[r] = f2bf(acc[mi][ni][r] + bias_v);
        if (valid)
          *(u16x4*)&Vpk[(size_t)(b * NHEAD + head) * VPLANE + VOFF(d, tok)] = pk;
      }
    }
  }
}

// ---------------------------------------------------------------------------
// Kernel 2: flash attention — barrier-free reg-fragment, all 16 K/V fragment
// loads of an iter issued upfront (kf/vf arrays) with rolling next-iter
// refill; grid (32 bh, 33 q) so all q-blocks of one bh share an XCD L2.
// ---------------------------------------------------------------------------
__global__ __launch_bounds__(256) void attn_kernel(
    const unsigned short* __restrict__ Qpk,
    const unsigned short* __restrict__ Kpk,
    const unsigned short* __restrict__ Vpk,
    unsigned short* __restrict__ ctxp)
{
  __shared__ unsigned short Ps[4][16][68];

  const int tid  = threadIdx.x;
  const int wave = tid >> 6;
  const int lane = tid & 63;
  const int quad = lane >> 4;
  const int l16  = lane & 15;
  const int bh   = blockIdx.x;           // linear%8 == bh%8 -> XCD-local K/V
  const int q0   = blockIdx.y * 64;
  const unsigned short* Qp = Qpk + (size_t)bh * QPLANE + lane * 8;
  const unsigned short* Kp = Kpk + (size_t)bh * QPLANE + lane * 8;
  const unsigned short* Vp = Vpk + (size_t)bh * VPLANE + lane * 8;

  const int qt = min((q0 >> 4) + wave, 128);
  bf16x8 aq[2];
#pragma unroll
  for (int c = 0; c < 2; c++) aq[c] = ldfrag(Qp + (size_t)(qt * 2 + c) * 512);

  u16x8 ones_u;
#pragma unroll
  for (int i = 0; i < 8; i++) ones_u[i] = 0x3F80;
  const bf16x8 ones = __builtin_bit_cast(bf16x8, ones_u);

  f32x4 oacc[4] = {};
  f32x4 lacc = {};

  // iter-0 K and V fragments all in flight before the loop
  bf16x8 kf[8], vf[8];
#pragma unroll
  for (int f = 0; f < 8; f++) kf[f] = ldfrag(Kp + (size_t)f * 512);
#pragma unroll
  for (int nt = 0; nt < 4; nt++)
#pragma unroll
    for (int c = 0; c < 2; c++) vf[nt * 2 + c] = ldfrag(Vp + (size_t)(nt * 65 + c) * 512);

  for (int it = 0; it < 32; it++) {
    // S = Q K^T (consumes kf)
    f32x4 sacc[4] = {};
#pragma unroll
    for (int nt = 0; nt < 4; nt++)
#pragma unroll
      for (int c = 0; c < 2; c++)
        sacc[nt] = __builtin_amdgcn_mfma_f32_16x16x32_bf16(aq[c], kf[nt * 2 + c], sacc[nt], 0, 0, 0);
    // refill kf for it+1 (lands during exp/Ps/PV below)
    if (it < 31) {
#pragma unroll
      for (int f = 0; f < 8; f++) kf[f] = ldfrag(Kp + (size_t)((it + 1) * 8 + f) * 512);
    }
    // p = exp2(s*C1 - C2) -> wave-private Ps (C-layout -> A-layout)
#pragma unroll
    for (int nt = 0; nt < 4; nt++)
#pragma unroll
      for (int rr = 0; rr < 4; rr++)
        Ps[wave][quad * 4 + rr][nt * 16 + l16] =
            f2bf_trunc(exp2f(__builtin_fmaf(sacc[nt][rr], EXP_C1, -EXP_C2)));

    // O += P V ; l += P @ ones (consumes vf)
#pragma unroll
    for (int c = 0; c < 2; c++) {
      u16x4 alo = *(const u16x4*)&Ps[wave][l16][c * 32 + quad * 8];
      u16x4 ahi = *(const u16x4*)&Ps[wave][l16][c * 32 + quad * 8 + 4];
      bf16x8 ap = __builtin_bit_cast(bf16x8,
          __builtin_shufflevector(alo, ahi, 0, 1, 2, 3, 4, 5, 6, 7));
#pragma unroll
      for (int nt = 0; nt < 4; nt++)
        oacc[nt] = __builtin_amdgcn_mfma_f32_16x16x32_bf16(ap, vf[nt * 2 + c], oacc[nt], 0, 0, 0);
      lacc = __builtin_amdgcn_mfma_f32_16x16x32_bf16(ap, ones, lacc, 0, 0, 0);
    }
    // refill vf for it+1
    if (it < 31) {
#pragma unroll
      for (int nt = 0; nt < 4; nt++)
#pragma unroll
        for (int c = 0; c < 2; c++)
          vf[nt * 2 + c] = ldfrag(Vp + (size_t)(nt * 65 + (it + 1) * 2 + c) * 512);
    }
  }

  // tail: keys 2048..2063 (keytile 128; V pad keys killed by P=0)
  {
    f32x4 s0 = {};
#pragma unroll
    for (int c = 0; c < 2; c++) {
      bf16x8 bk = ldfrag(Kp + (size_t)(128 * 2 + c) * 512);
      s0 = __builtin_amdgcn_mfma_f32_16x16x32_bf16(aq[c], bk, s0, 0, 0, 0);
    }
#pragma unroll
    for (int rr = 0; rr < 4; rr++) {
      Ps[wave][quad * 4 + rr][l16]      = f2bf_trunc(exp2f(__builtin_fmaf(s0[rr], EXP_C1, -EXP_C2)));
      Ps[wave][quad * 4 + rr][16 + l16] = 0;
    }
    u16x4 alo = *(const u16x4*)&Ps[wave][l16][quad * 8];
    u16x4 ahi = *(const u16x4*)&Ps[wave][l16][quad * 8 + 4];
    bf16x8 ap = __builtin_bit_cast(bf16x8,
        __builtin_shufflevector(alo, ahi, 0, 1, 2, 3, 4, 5, 6, 7));
#pragma unroll
    for (int nt = 0; nt < 4; nt++) {
      bf16x8 bv = ldfrag(Vp + (size_t)(nt * 65 + 64) * 512);
      oacc[nt] = __builtin_amdgcn_mfma_f32_16x16x32_bf16(ap, bv, oacc[nt], 0, 0, 0);
    }
    lacc = __builtin_amdgcn_mfma_f32_16x16x32_bf16(ap, ones, lacc, 0, 0, 0);
  }

  const int b = bh >> 4, h = bh & 15;
  float rl[4];
#pragma unroll
  for (int rr = 0; rr < 4; rr++) rl[rr] = 1.f / lacc[rr];
#pragma unroll
  for (int nt = 0; nt < 4; nt++) {
#pragma unroll
    for (int rr = 0; rr < 4; rr++) {
      int token = q0 + wave * 16 + quad * 4 + rr;
      if (token < NTOK) {
        int row = (token < 2048) ? (b * 2048 + token) : (4096 + b * NA + (token - 2048));
        int col = h * HDIM + nt * 16 + l16;
        ctxp[POFF(row, col)] = f2bf(oacc[nt][rr] * rl[rr]);
      }
    }
  }
}

// ---------------------------------------------------------------------------
// Kernel 3: output projection — 64x64 tiles, grid (16 n, 66 m) = 1056 blocks.
// ---------------------------------------------------------------------------
__global__ __launch_bounds__(256) void proj_kernel(
    const unsigned short* __restrict__ ctxp, const unsigned short* __restrict__ Wb,
    const float* __restrict__ bp, const float* __restrict__ bpa,
    float* __restrict__ out)
{
  const int tid  = threadIdx.x;
  const int w    = tid >> 6;
  const int lane = tid & 63;
  const int quad = lane >> 4;
  const int l16  = lane & 15;
  const int mh   = w & 1;
  const int nh   = w >> 1;
  const int m0   = blockIdx.y * 64;
  const int n0   = blockIdx.x * 64;
  const bool atile = (blockIdx.y >= 64);

  const unsigned short* Wz = Wb + (size_t)(atile ? 7 : 6) * WSZ;
  const float* bias = atile ? bpa : bp;

  const int Mt = (m0 >> 4) + mh * 2;
  const int Nt = (n0 >> 4) + nh * 2;
  const unsigned short* pa = ctxp + (size_t)Mt * 32 * 512 + lane * 8;
  const unsigned short* pb = Wz + (size_t)Nt * 32 * 512 + lane * 8;

  f32x4 acc[2][2] = {};
  bf16x8 af[2][2], bf[2][2];

#pragma unroll
  for (int mi = 0; mi < 2; mi++) af[0][mi] = ldfrag(pa + (size_t)(mi * 32) * 512);
#pragma unroll
  for (int ni = 0; ni < 2; ni++) bf[0][ni] = ldfrag(pb + (size_t)(ni * 32) * 512);

  for (int kt = 0; kt < 32; kt++) {
    const int cb = kt & 1, nb = cb ^ 1;
    if (kt < 31) {
#pragma unroll
      for (int mi = 0; mi < 2; mi++) af[nb][mi] = ldfrag(pa + (size_t)(mi * 32 + kt + 1) * 512);
#pragma unroll
      for (int ni = 0; ni < 2; ni++) bf[nb][ni] = ldfrag(pb + (size_t)(ni * 32 + kt + 1) * 512);
    }
#pragma unroll
    for (int mi = 0; mi < 2; mi++)
#pragma unroll
      for (int ni = 0; ni < 2; ni++)
        acc[mi][ni] = __builtin_amdgcn_mfma_f32_16x16x32_bf16(af[cb][mi], bf[cb][ni], acc[mi][ni], 0, 0, 0);
  }

#pragma unroll
  for (int mi = 0; mi < 2; mi++) {
    const int rgb = m0 + mh * 32 + mi * 16 + quad * 4;
#pragma unroll
    for (int ni = 0; ni < 2; ni++) {
      const int gcol = n0 + nh * 32 + ni * 16 + l16;
      const float bias_v = bias[gcol];
#pragma unroll
      for (int r = 0; r < 4; r++) {
        int rg = rgb + r;
        if (rg < MROWS) out[(size_t)rg * HID + gcol] = acc[mi][ni][r] + bias_v;
      }
    }
  }
}

// ---------------------------------------------------------------------------
extern "C" void kernel_launch(void* const* d_in, const int* in_sizes, int n_in,
                              void* d_out, int out_size, void* d_ws, size_t ws_size,
                              hipStream_t stream) {
  const float* A[18];
  if (in_sizes[0] == HID * HID) {
    for (int i = 0; i < 18; i++) A[i] = (const float*)d_in[i];
  } else {
    A[16] = (const float*)d_in[0];
    A[17] = (const float*)d_in[1];
    for (int i = 0; i < 16; i++) A[i] = (const float*)d_in[i + 2];
  }
  const float *Wq = A[0], *bq = A[1], *Wk = A[2], *bk = A[3], *Wv = A[4], *bv = A[5];
  const float *Wqa = A[6], *bqa = A[7], *Wka = A[8], *bka = A[9], *Wva = A[10], *bva = A[11];
  const float *Wp = A[12], *bp = A[13], *Wpa = A[14], *bpa = A[15];
  const float *video = A[16], *action = A[17];
  float* out = (float*)d_out;

  unsigned short* Wb   = (unsigned short*)d_ws;                 // 8 x 1M packed
  unsigned short* Xp   = Wb + (size_t)8 * WSZ;                  // MPAD x 1024 packed
  unsigned short* Qpk  = Xp + (size_t)(MPAD / 16) * 32 * 512;   // 32 planes
  unsigned short* Kpk  = Qpk + (size_t)32 * QPLANE;
  unsigned short* Vpk  = Kpk + (size_t)32 * QPLANE;
  unsigned short* ctxp = Vpk + (size_t)32 * VPLANE;             // MPAD x 1024 packed

  dim3 g0(512, 13);
  cvt_kernel<<<g0, 256, 0, stream>>>(Wq, Wk, Wv, Wqa, Wka, Wva, Wp, Wpa,
                                     video, action, Wb, Xp);
  dim3 g1(8, 3, 33);
  qkv_kernel<<<g1, 512, 0, stream>>>(Xp, Wb, bq, bk, bv, bqa, bka, bva,
                                     Qpk, Kpk, Vpk);
  dim3 g2(BSZ * NHEAD, 33);
  attn_kernel<<<g2, 256, 0, stream>>>(Qpk, Kpk, Vpk, ctxp);
  dim3 g3(16, 66);
  proj_kernel<<<g3, 256, 0, stream>>>(ctxp, Wb, bp, bpa, out);
}

// Round 9
// 313.974 us; speedup vs baseline: 1.2328x; 1.0031x over previous
//
#include <hip/hip_runtime.h>
#include <stdint.h>

#define HID   1024
#define NHEAD 16
#define HDIM  64
#define NV    2048
#define NA    16
#define NTOK  2064
#define BSZ   2
#define MROWS 4128    // 4096 video + 32 action (valid rows)
#define MPAD  4224    // padded to 33*128 (rows 4128+ garbage, masked on output)
#define WSZ   1048576
// p = exp2(s * SCALE * log2(e) - 16)   [fixed-max softmax, exact after divide]
#define EXP_C1 0.18033688011112042f
#define EXP_C2 16.0f

// fragment-packed offsets: element (row r, col k) of a (16-row x 32-col) MFMA
// fragment tile stored lane-linear: lane = quad*16 + r15 reads 8 consecutive k.
#define POFF(r,k)  (((((r)>>4)*32  + ((k)>>5))*512) + ((((k)>>3)&3)*128) + (((r)&15)*8) + ((k)&7))   // 1024-col mats
#define QOFF(t,d)  (((((t)>>4)*2   + ((d)>>5))*512) + ((((d)>>3)&3)*128) + (((t)&15)*8) + ((d)&7))   // Q/K planes (64 col)
#define VOFF(d,ky) (((((d)>>4)*65  + ((ky)>>5))*512) + ((((ky)>>3)&3)*128) + (((d)&15)*8) + ((ky)&7)) // V^T planes (2080 keys padded)
#define QPLANE (129*2*512)    // 132096 elems per (b,h)
#define VPLANE (4*65*512)     // 133120 elems per (b,h)

typedef __bf16 bf16x8 __attribute__((ext_vector_type(8)));
typedef unsigned short u16x8 __attribute__((ext_vector_type(8)));
typedef unsigned short u16x4 __attribute__((ext_vector_type(4)));
typedef float f32x4 __attribute__((ext_vector_type(4)));

__device__ __forceinline__ unsigned short f2bf(float f) {  // RNE
  unsigned u = __builtin_bit_cast(unsigned, f);
  u += 0x7FFFu + ((u >> 16) & 1u);
  return (unsigned short)(u >> 16);
}
__device__ __forceinline__ unsigned short f2bf_trunc(float f) {
  return (unsigned short)(__builtin_bit_cast(unsigned, f) >> 16);
}
__device__ __forceinline__ unsigned pack2bf(float a, float b) {  // [lo=a, hi=b]
  return (__builtin_bit_cast(unsigned, a) >> 16) |
         (__builtin_bit_cast(unsigned, b) & 0xFFFF0000u);
}
__device__ __forceinline__ bf16x8 ldfrag(const unsigned short* p) {
  return __builtin_bit_cast(bf16x8, *(const u16x8*)p);
}

// ---------------------------------------------------------------------------
// Kernel 0: fp32 -> bf16 convert + fragment-pack.
// ---------------------------------------------------------------------------
__global__ __launch_bounds__(256) void cvt_kernel(
    const float* __restrict__ W0, const float* __restrict__ W1,
    const float* __restrict__ W2, const float* __restrict__ W3,
    const float* __restrict__ W4, const float* __restrict__ W5,
    const float* __restrict__ W6, const float* __restrict__ W7,
    const float* __restrict__ video, const float* __restrict__ action,
    unsigned short* __restrict__ Wb, unsigned short* __restrict__ Xp)
{
  const int y = blockIdx.y;
  const size_t idx = ((size_t)blockIdx.x * 256 + threadIdx.x) * 8;
  const float* src; unsigned short* dstbase; int row;
  if (y < 8) {
    const float* Ws[8] = {W0, W1, W2, W3, W4, W5, W6, W7};
    src = Ws[y] + idx; dstbase = Wb + (size_t)y * WSZ; row = (int)(idx >> 10);
  } else if (y < 12) {
    src = video + (size_t)(y - 8) * WSZ + idx; dstbase = Xp;
    row = ((y - 8) << 10) + (int)(idx >> 10);
  } else {
    if (idx >= (size_t)BSZ * NA * HID) return;
    src = action + idx; dstbase = Xp; row = 4096 + (int)(idx >> 10);
  }
  const int k0 = (int)(idx & 1023);
  float4 f0 = *(const float4*)src;
  float4 f1 = *(const float4*)(src + 4);
  u16x8 v;
  v[0]=f2bf(f0.x); v[1]=f2bf(f0.y); v[2]=f2bf(f0.z); v[3]=f2bf(f0.w);
  v[4]=f2bf(f1.x); v[5]=f2bf(f1.y); v[6]=f2bf(f1.z); v[7]=f2bf(f1.w);
  *(u16x8*)(dstbase + POFF(row, k0)) = v;
}

// row -> (batch, token) in the joint token space
__device__ __forceinline__ void row2bt(int rg, int& b, int& tok, bool& valid) {
  if (rg < 4096) { b = rg >> 11; tok = rg & 2047; valid = true; }
  else { int t = rg - 4096; b = t >> 4; tok = 2048 + (t & 15); valid = rg < MROWS; }
}

// ---------------------------------------------------------------------------
// Kernel 1: QKV GEMM — barrier/LDS-free reg-fragment GEMM, 512-thr blocks.
// grid (8 n, 3 z, 33 m); block = 8 waves, wave = 32m x 64n (acc[2][4]).
// ---------------------------------------------------------------------------
__global__ __launch_bounds__(512) void qkv_kernel(
    const unsigned short* __restrict__ Xp, const unsigned short* __restrict__ Wb,
    const float* __restrict__ bq, const float* __restrict__ bk,
    const float* __restrict__ bv, const float* __restrict__ bqa,
    const float* __restrict__ bka, const float* __restrict__ bva,
    unsigned short* __restrict__ Qpk, unsigned short* __restrict__ Kpk,
    unsigned short* __restrict__ Vpk)
{
  const int tid  = threadIdx.x;
  const int w    = tid >> 6;
  const int lane = tid & 63;
  const int quad = lane >> 4;
  const int l16  = lane & 15;
  const int mh   = w & 3;        // m quarter (32 rows)
  const int nh   = w >> 2;       // n half (64 cols)
  const int n0   = blockIdx.x * 128;
  const int z    = blockIdx.y;
  const int m0   = blockIdx.z * 128;
  const bool atile = (blockIdx.z == 32);

  const unsigned short* Wz = Wb + (size_t)(atile ? 3 + z : z) * WSZ;
  const float* bias = (z == 0) ? (atile ? bqa : bq)
                    : (z == 1) ? (atile ? bka : bk)
                               : (atile ? bva : bv);

  const int Mt = (m0 >> 4) + mh * 2;
  const int Nt = (n0 >> 4) + nh * 4;
  const unsigned short* pa = Xp + (size_t)Mt * 32 * 512 + lane * 8;
  const unsigned short* pb = Wz + (size_t)Nt * 32 * 512 + lane * 8;

  f32x4 acc[2][4] = {};
  bf16x8 af[2][2], bf[2][4];

#pragma unroll
  for (int mi = 0; mi < 2; mi++) af[0][mi] = ldfrag(pa + (size_t)(mi * 32) * 512);
#pragma unroll
  for (int ni = 0; ni < 4; ni++) bf[0][ni] = ldfrag(pb + (size_t)(ni * 32) * 512);

  for (int kt = 0; kt < 32; kt++) {
    const int cb = kt & 1, nb = cb ^ 1;
    if (kt < 31) {
#pragma unroll
      for (int mi = 0; mi < 2; mi++) af[nb][mi] = ldfrag(pa + (size_t)(mi * 32 + kt + 1) * 512);
#pragma unroll
      for (int ni = 0; ni < 4; ni++) bf[nb][ni] = ldfrag(pb + (size_t)(ni * 32 + kt + 1) * 512);
    }
#pragma unroll
    for (int mi = 0; mi < 2; mi++)
#pragma unroll
      for (int ni = 0; ni < 4; ni++)
        acc[mi][ni] = __builtin_amdgcn_mfma_f32_16x16x32_bf16(af[cb][mi], bf[cb][ni], acc[mi][ni], 0, 0, 0);
  }

  if (z < 2) {
    unsigned short* O = (z == 0) ? Qpk : Kpk;
#pragma unroll
    for (int mi = 0; mi < 2; mi++) {
      const int rgb = m0 + mh * 32 + mi * 16 + quad * 4;
#pragma unroll
      for (int ni = 0; ni < 4; ni++) {
        const int gcol = n0 + nh * 64 + ni * 16 + l16;
        const int head = gcol >> 6, col = gcol & 63;
        const float bias_v = bias[gcol];
        const int seg = (col >= 40) ? 2 : (col >= 20) ? 1 : 0;
        const int tin = col - seg * 20;
        const float om = exp2f(-(float)(tin >> 1) * 1.3287712379549449f);
        const bool evn = !(tin & 1);
#pragma unroll
        for (int r = 0; r < 4; r++) {
          int rg = rgb + r;
          int b, tok; bool valid;
          row2bt(rg, b, tok, valid);
          float val = acc[mi][ni][r] + bias_v;
          float part = __shfl_xor(val, 1);
          if (tok < 2048 && col < 60) {
            int dp = tok >> 8, hp = (tok >> 4) & 15, wp = tok & 15;
            float pos = (seg == 0) ? (float)dp : (seg == 1) ? (float)hp : (float)wp;
            float fr = pos * om;
            float cs = cosf(fr), sn = sinf(fr);
            val = evn ? (val * cs - part * sn) : (val * cs + part * sn);
          }
          if (valid)
            O[(size_t)(b * NHEAD + head) * QPLANE + QOFF(tok, col)] = f2bf(val);
        }
      }
    }
  } else {
#pragma unroll
    for (int mi = 0; mi < 2; mi++) {
      const int rgb = m0 + mh * 32 + mi * 16 + quad * 4;
      int b, tok; bool valid;
      row2bt(rgb, b, tok, valid);
#pragma unroll
      for (int ni = 0; ni < 4; ni++) {
        const int gcol = n0 + nh * 64 + ni * 16 + l16;
        const int head = gcol >> 6, d = gcol & 63;
        const float bias_v = bias[gcol];
        u16x4 pk;
#pragma unroll
        for (int r = 0; r < 4; r++) pk[r] = f2bf(acc[mi][ni][r] + bias_v);
        if (valid)
          *(u16x4*)&Vpk[(size_t)(b * NHEAD + head) * VPLANE + VOFF(d, tok)] = pk;
      }
    }
  }
}

// ---------------------------------------------------------------------------
// Kernel 2: flash attention — transposed-score (S^T = K Q^T) formulation.
// C-layout P^T repacks to B-frags via 8 v_perm + 4 ds_write_b64 + 2 ds_read_b128.
// O^T = V^T P^T ; l = ones·P^T (broadcast per q-lane). Barrier-free.
// grid (32 bh, 33 q); sched_barrier stops refill-load sinking.
// ---------------------------------------------------------------------------
__global__ __launch_bounds__(256) void attn_kernel(
    const unsigned short* __restrict__ Qpk,
    const unsigned short* __restrict__ Kpk,
    const unsigned short* __restrict__ Vpk,
    unsigned short* __restrict__ ctxp)
{
  __shared__ unsigned int Pt[4][2][64][4];   // [wave][c-frag][lane][dword] 8 KB

  const int tid  = threadIdx.x;
  const int wave = tid >> 6;
  const int lane = tid & 63;
  const int quad = lane >> 4;
  const int l16  = lane & 15;
  const int bh   = blockIdx.x;           // linear%8 == bh%8 -> XCD-local K/V
  const int q0   = blockIdx.y * 64;
  const unsigned short* Qp = Qpk + (size_t)bh * QPLANE + lane * 8;
  const unsigned short* Kp = Kpk + (size_t)bh * QPLANE + lane * 8;
  const unsigned short* Vp = Vpk + (size_t)bh * VPLANE + lane * 8;

  const int qt = min((q0 >> 4) + wave, 128);
  bf16x8 aq[2];   // B operand: n = query (lane&15), k = d
#pragma unroll
  for (int c = 0; c < 2; c++) aq[c] = ldfrag(Qp + (size_t)(qt * 2 + c) * 512);

  u16x8 ones_u;
#pragma unroll
  for (int i = 0; i < 8; i++) ones_u[i] = 0x3F80;
  const bf16x8 ones = __builtin_bit_cast(bf16x8, ones_u);

  f32x4 oacc[4] = {};   // O^T: per nt d-tile; m=d (quad*4+r), n=q (l16)
  f32x4 lacc = {};

  // iter-0 K and V fragments in flight
  bf16x8 kf[8], vf[8];
#pragma unroll
  for (int f = 0; f < 8; f++) kf[f] = ldfrag(Kp + (size_t)f * 512);
#pragma unroll
  for (int nt = 0; nt < 4; nt++)
#pragma unroll
    for (int c = 0; c < 2; c++) vf[nt * 2 + c] = ldfrag(Vp + (size_t)(nt * 65 + c) * 512);

  for (int it = 0; it < 32; it++) {
    // S^T = K Q^T : sacc[f] m=key (f*16+quad*4+r), n=q (l16)
    f32x4 sacc[4] = {};
#pragma unroll
    for (int f = 0; f < 4; f++)
#pragma unroll
      for (int c = 0; c < 2; c++)
        sacc[f] = __builtin_amdgcn_mfma_f32_16x16x32_bf16(kf[f * 2 + c], aq[c], sacc[f], 0, 0, 0);
    // refill kf for it+1
    if (it < 31) {
#pragma unroll
      for (int f = 0; f < 8; f++) kf[f] = ldfrag(Kp + (size_t)((it + 1) * 8 + f) * 512);
    }
    // exp + pack pairs + scatter into B-frag-packed LDS
#pragma unroll
    for (int f = 0; f < 4; f++) {
      float e0 = exp2f(__builtin_fmaf(sacc[f][0], EXP_C1, -EXP_C2));
      float e1 = exp2f(__builtin_fmaf(sacc[f][1], EXP_C1, -EXP_C2));
      float e2 = exp2f(__builtin_fmaf(sacc[f][2], EXP_C1, -EXP_C2));
      float e3 = exp2f(__builtin_fmaf(sacc[f][3], EXP_C1, -EXP_C2));
      const int c  = f >> 1;
      const int tq = (f & 1) * 2 + (quad >> 1);
      const int j0 = (quad & 1) * 2;
      uint2 w2; w2.x = pack2bf(e0, e1); w2.y = pack2bf(e2, e3);
      *(uint2*)&Pt[wave][c][tq * 16 + l16][j0] = w2;
    }
    // O^T += V^T P^T ; l += ones·P^T
#pragma unroll
    for (int c = 0; c < 2; c++) {
      bf16x8 ptf = __builtin_bit_cast(bf16x8, *(const u16x8*)&Pt[wave][c][lane][0]);
#pragma unroll
      for (int nt = 0; nt < 4; nt++)
        oacc[nt] = __builtin_amdgcn_mfma_f32_16x16x32_bf16(vf[nt * 2 + c], ptf, oacc[nt], 0, 0, 0);
      lacc = __builtin_amdgcn_mfma_f32_16x16x32_bf16(ones, ptf, lacc, 0, 0, 0);
    }
    // refill vf for it+1
    if (it < 31) {
#pragma unroll
      for (int nt = 0; nt < 4; nt++)
#pragma unroll
        for (int c = 0; c < 2; c++)
          vf[nt * 2 + c] = ldfrag(Vp + (size_t)(nt * 65 + (it + 1) * 2 + c) * 512);
    }
    __builtin_amdgcn_sched_barrier(0);  // keep refills in this iteration
  }

  // ---- tail: keys 2048..2063 (16 valid; V pad keys killed by P^T zeros) ----
  {
    f32x4 s0 = {};
#pragma unroll
    for (int c = 0; c < 2; c++) {
      bf16x8 bk = ldfrag(Kp + (size_t)(128 * 2 + c) * 512);
      s0 = __builtin_amdgcn_mfma_f32_16x16x32_bf16(bk, aq[c], s0, 0, 0, 0);
    }
    // zero the k=16..31 region of frag 0
    *(uint2*)&Pt[wave][0][32 + (lane >> 1)][(lane & 1) * 2] = make_uint2(0u, 0u);
    {
      float e0 = exp2f(__builtin_fmaf(s0[0], EXP_C1, -EXP_C2));
      float e1 = exp2f(__builtin_fmaf(s0[1], EXP_C1, -EXP_C2));
      float e2 = exp2f(__builtin_fmaf(s0[2], EXP_C1, -EXP_C2));
      float e3 = exp2f(__builtin_fmaf(s0[3], EXP_C1, -EXP_C2));
      const int tq = quad >> 1;
      const int j0 = (quad & 1) * 2;
      uint2 w2; w2.x = pack2bf(e0, e1); w2.y = pack2bf(e2, e3);
      *(uint2*)&Pt[wave][0][tq * 16 + l16][j0] = w2;
    }
    bf16x8 ptf = __builtin_bit_cast(bf16x8, *(const u16x8*)&Pt[wave][0][lane][0]);
#pragma unroll
    for (int nt = 0; nt < 4; nt++) {
      bf16x8 bv = ldfrag(Vp + (size_t)(nt * 65 + 64) * 512);
      oacc[nt] = __builtin_amdgcn_mfma_f32_16x16x32_bf16(bv, ptf, oacc[nt], 0, 0, 0);
    }
    lacc = __builtin_amdgcn_mfma_f32_16x16x32_bf16(ones, ptf, lacc, 0, 0, 0);
  }

  // epilogue: every lane's query is l16; l[q] already in lacc (rows identical)
  const int b = bh >> 4, h = bh & 15;
  const float rl = 1.f / lacc[0];
  const int token = q0 + wave * 16 + l16;
  if (token < NTOK) {
    const int row = (token < 2048) ? (b * 2048 + token) : (4096 + b * NA + (token - 2048));
#pragma unroll
    for (int nt = 0; nt < 4; nt++) {
      const int col = h * HDIM + nt * 16 + quad * 4;   // + r
      u16x4 pk;
#pragma unroll
      for (int r = 0; r < 4; r++) pk[r] = f2bf(oacc[nt][r] * rl);
      *(u16x4*)&ctxp[POFF(row, col)] = pk;
    }
  }
}

// ---------------------------------------------------------------------------
// Kernel 3: output projection — 64x64 tiles, grid (16 n, 66 m) = 1056 blocks.
// ---------------------------------------------------------------------------
__global__ __launch_bounds__(256) void proj_kernel(
    const unsigned short* __restrict__ ctxp, const unsigned short* __restrict__ Wb,
    const float* __restrict__ bp, const float* __restrict__ bpa,
    float* __restrict__ out)
{
  const int tid  = threadIdx.x;
  const int w    = tid >> 6;
  const int lane = tid & 63;
  const int quad = lane >> 4;
  const int l16  = lane & 15;
  const int mh   = w & 1;
  const int nh   = w >> 1;
  const int m0   = blockIdx.y * 64;
  const int n0   = blockIdx.x * 64;
  const bool atile = (blockIdx.y >= 64);

  const unsigned short* Wz = Wb + (size_t)(atile ? 7 : 6) * WSZ;
  const float* bias = atile ? bpa : bp;

  const int Mt = (m0 >> 4) + mh * 2;
  const int Nt = (n0 >> 4) + nh * 2;
  const unsigned short* pa = ctxp + (size_t)Mt * 32 * 512 + lane * 8;
  const unsigned short* pb = Wz + (size_t)Nt * 32 * 512 + lane * 8;

  f32x4 acc[2][2] = {};
  bf16x8 af[2][2], bf[2][2];

#pragma unroll
  for (int mi = 0; mi < 2; mi++) af[0][mi] = ldfrag(pa + (size_t)(mi * 32) * 512);
#pragma unroll
  for (int ni = 0; ni < 2; ni++) bf[0][ni] = ldfrag(pb + (size_t)(ni * 32) * 512);

  for (int kt = 0; kt < 32; kt++) {
    const int cb = kt & 1, nb = cb ^ 1;
    if (kt < 31) {
#pragma unroll
      for (int mi = 0; mi < 2; mi++) af[nb][mi] = ldfrag(pa + (size_t)(mi * 32 + kt + 1) * 512);
#pragma unroll
      for (int ni = 0; ni < 2; ni++) bf[nb][ni] = ldfrag(pb + (size_t)(ni * 32 + kt + 1) * 512);
    }
#pragma unroll
    for (int mi = 0; mi < 2; mi++)
#pragma unroll
      for (int ni = 0; ni < 2; ni++)
        acc[mi][ni] = __builtin_amdgcn_mfma_f32_16x16x32_bf16(af[cb][mi], bf[cb][ni], acc[mi][ni], 0, 0, 0);
  }

#pragma unroll
  for (int mi = 0; mi < 2; mi++) {
    const int rgb = m0 + mh * 32 + mi * 16 + quad * 4;
#pragma unroll
    for (int ni = 0; ni < 2; ni++) {
      const int gcol = n0 + nh * 32 + ni * 16 + l16;
      const float bias_v = bias[gcol];
#pragma unroll
      for (int r = 0; r < 4; r++) {
        int rg = rgb + r;
        if (rg < MROWS) out[(size_t)rg * HID + gcol] = acc[mi][ni][r] + bias_v;
      }
    }
  }
}

// ---------------------------------------------------------------------------
extern "C" void kernel_launch(void* const* d_in, const int* in_sizes, int n_in,
                              void* d_out, int out_size, void* d_ws, size_t ws_size,
                              hipStream_t stream) {
  const float* A[18];
  if (in_sizes[0] == HID * HID) {
    for (int i = 0; i < 18; i++) A[i] = (const float*)d_in[i];
  } else {
    A[16] = (const float*)d_in[0];
    A[17] = (const float*)d_in[1];
    for (int i = 0; i < 16; i++) A[i] = (const float*)d_in[i + 2];
  }
  const float *Wq = A[0], *bq = A[1], *Wk = A[2], *bk = A[3], *Wv = A[4], *bv = A[5];
  const float *Wqa = A[6], *bqa = A[7], *Wka = A[8], *bka = A[9], *Wva = A[10], *bva = A[11];
  const float *Wp = A[12], *bp = A[13], *Wpa = A[14], *bpa = A[15];
  const float *video = A[16], *action = A[17];
  float* out = (float*)d_out;

  unsigned short* Wb   = (unsigned short*)d_ws;                 // 8 x 1M packed
  unsigned short* Xp   = Wb + (size_t)8 * WSZ;                  // MPAD x 1024 packed
  unsigned short* Qpk  = Xp + (size_t)(MPAD / 16) * 32 * 512;   // 32 planes
  unsigned short* Kpk  = Qpk + (size_t)32 * QPLANE;
  unsigned short* Vpk  = Kpk + (size_t)32 * QPLANE;
  unsigned short* ctxp = Vpk + (size_t)32 * VPLANE;             // MPAD x 1024 packed

  dim3 g0(512, 13);
  cvt_kernel<<<g0, 256, 0, stream>>>(Wq, Wk, Wv, Wqa, Wka, Wva, Wp, Wpa,
                                     video, action, Wb, Xp);
  dim3 g1(8, 3, 33);
  qkv_kernel<<<g1, 512, 0, stream>>>(Xp, Wb, bq, bk, bv, bqa, bka, bva,
                                     Qpk, Kpk, Vpk);
  dim3 g2(BSZ * NHEAD, 33);
  attn_kernel<<<g2, 256, 0, stream>>>(Qpk, Kpk, Vpk, ctxp);
  dim3 g3(16, 66);
  proj_kernel<<<g3, 256, 0, stream>>>(ctxp, Wb, bp, bpa, out);
}